// Round 1
// baseline (1845.643 us; speedup 1.0000x reference)
//
#include <hip/hip_runtime.h>
#include <math.h>

#define NA 2048          // atoms
#define KN 24            // neighbors per atom
#define NE (NA*KN)       // edges = 49152
#define NDIM 128         // node dim
#define EDIM 64          // rbf dim
#define HDIM 256         // hidden dim
#define NLAYER 4
#define MAXDEG 256       // cap on in-degree for CSR
#define KCAP 1024        // candidate buffer for knn

__device__ __forceinline__ float siluf(float x) { return x / (1.0f + expf(-x)); }

struct Lat { float lx, xy, xz, ly, yz, lz; };

__device__ __forceinline__ Lat make_lattice(const float* lengths, const float* angles) {
    const float deg = 0.017453292519943295f;
    float a = lengths[0], b = lengths[1], c = lengths[2];
    float al = angles[0]*deg, be = angles[1]*deg, ga = angles[2]*deg;
    Lat L;
    L.lx = a;
    L.xy = b * cosf(ga);
    L.xz = c * cosf(be);
    L.ly = b * sinf(ga);
    L.yz = (b*c*cosf(al) - L.xy*L.xz) / L.ly;
    L.lz = sqrtf(c*c - L.xz*L.xz - L.yz*L.yz);
    return L;
}

// cart = frac @ lattice; sv[s] = shift[s] @ lattice (shift order: i outer, k inner, in (-1,0,1))
__global__ void setup_kernel(const float* __restrict__ frac, const float* __restrict__ lengths,
                             const float* __restrict__ angles, float* __restrict__ cart,
                             float* __restrict__ sv) {
    int i = blockIdx.x*blockDim.x + threadIdx.x;
    Lat L = make_lattice(lengths, angles);
    if (i < NA) {
        float f0 = frac[i*3], f1 = frac[i*3+1], f2 = frac[i*3+2];
        cart[i*3+0] = f0*L.lx + f1*L.xy + f2*L.xz;
        cart[i*3+1] = f1*L.ly + f2*L.yz;
        cart[i*3+2] = f2*L.lz;
    }
    if (i < 27) {
        float s0 = (float)(i/9 - 1), s1 = (float)((i/3)%3 - 1), s2 = (float)(i%3 - 1);
        sv[i*3+0] = s0*L.lx + s1*L.xy + s2*L.xz;
        sv[i*3+1] = s1*L.ly + s2*L.yz;
        sv[i*3+2] = s2*L.lz;
    }
}

// Per-atom top-24 neighbor search. Collect candidates with dist<R (R grows if <24 found),
// then 24x argmin extraction by (dist, flat_idx) to match jax.lax.top_k tie-breaking.
__global__ __launch_bounds__(256) void knn_kernel(const float* __restrict__ cart,
        const float* __restrict__ sv, int* __restrict__ dstl, float* __restrict__ de) {
    __shared__ float scart[NA*3];
    __shared__ float ssv[81];
    __shared__ float sd[KCAP];
    __shared__ int   sf[KCAP];
    __shared__ unsigned long long rk[256];
    __shared__ int scnt;
    const int t = threadIdx.x;
    const int i = blockIdx.x;
    for (int q = t; q < NA*3; q += 256) scart[q] = cart[q];
    if (t < 81) ssv[t] = sv[t];
    __syncthreads();
    const float cx = scart[i*3], cy = scart[i*3+1], cz = scart[i*3+2];
    float R = 2.8f;
    int cnt = 0;
    for (int attempt = 0; attempt < 8; ++attempt) {
        if (t == 0) scnt = 0;
        __syncthreads();
        for (int f = t; f < 27*NA; f += 256) {
            const int s = f >> 11, j = f & (NA-1);
            const float px = scart[j*3]   + ssv[s*3];
            const float py = scart[j*3+1] + ssv[s*3+1];
            const float pz = scart[j*3+2] + ssv[s*3+2];
            const float dx = px-cx, dy = py-cy, dz = pz-cz;
            const float dist = sqrtf(fmaxf(dx*dx+dy*dy+dz*dz, 1e-12f));
            if (dist > 0.01f && dist < R) {
                int slot = atomicAdd(&scnt, 1);
                if (slot < KCAP) { sd[slot] = dist; sf[slot] = f; }
            }
        }
        __syncthreads();
        cnt = scnt < KCAP ? scnt : KCAP;
        if (cnt >= KN) break;
        R = fminf(R * 1.6f, 8.0f);
        __syncthreads();
    }
    for (int q = cnt + t; q < KCAP; q += 256) { sd[q] = INFINITY; sf[q] = 0; }
    __syncthreads();
    for (int k = 0; k < KN; ++k) {
        unsigned long long best = ~0ull;
        for (int q = t; q < KCAP; q += 256) {
            // key: distance bits (32) | flat idx (16) | slot (10); positive-float bits are monotone
            unsigned long long key = ((unsigned long long)__float_as_uint(sd[q]) << 26)
                                   | ((unsigned long long)(unsigned)sf[q] << 10) | (unsigned)q;
            best = best < key ? best : key;
        }
        rk[t] = best;
        __syncthreads();
        for (int off = 128; off > 0; off >>= 1) {
            if (t < off) { if (rk[t+off] < rk[t]) rk[t] = rk[t+off]; }
            __syncthreads();
        }
        if (t == 0) {
            int slot = (int)(rk[0] & 1023u);
            dstl[i*KN + k] = sf[slot] & (NA-1);
            de[i*KN + k]   = sd[slot];
            sd[slot] = INFINITY;
        }
        __syncthreads();
    }
}

__global__ void rbf_kernel(const float* __restrict__ de, float* __restrict__ rbf) {
    int idx = blockIdx.x*256 + threadIdx.x;
    if (idx >= NE*EDIM) return;
    int e = idx >> 6, c = idx & 63;
    float d = de[e];
    float center = (8.0f/63.0f) * (float)c;
    float diff = d - center;
    float g = expf(diff*diff * -32.0f);                    // widths=0.125 -> 1/(2w^2)=32
    float cv = 0.5f * (cosf(d * (float)(M_PI/8.0)) + 1.0f); // d<8 guaranteed
    rbf[idx] = g * cv;
}

// Deterministic CSR-by-dst: one wave per node scans all edges in order, ballot-ranked placement.
__global__ void csr_kernel(const int* __restrict__ dstl, int* __restrict__ ccnt,
                           int* __restrict__ cedg) {
    const int j = blockIdx.x;
    const int lane = threadIdx.x;       // blockDim = 64
    int cnt = 0;
    for (int base = 0; base < NE; base += 64) {
        int e = base + lane;
        bool match = (dstl[e] == j);
        unsigned long long mask = __ballot(match);
        int rank = __popcll(mask & ((1ull << lane) - 1ull));
        if (match && cnt + rank < MAXDEG) cedg[(size_t)j*MAXDEG + cnt + rank] = e;
        cnt += __popcll(mask);
    }
    if (lane == 0) ccnt[j] = cnt < MAXDEG ? cnt : MAXDEG;
}

__global__ void nf_init_kernel(const int* __restrict__ atom_types, const float* __restrict__ ts,
                               const float* __restrict__ emb, const float* __restrict__ tW,
                               const float* __restrict__ tb, float* __restrict__ nf) {
    int i = blockIdx.x, c = threadIdx.x;  // 128 threads
    float acc = emb[atom_types[i]*NDIM + c] + tb[c];
    for (int kk = 0; kk < 128; ++kk) acc += ts[i*128 + kk] * tW[kk*NDIM + c];
    nf[i*NDIM + c] = acc;
}

// fp32 tiled GEMM: 64x64 tile, BK=16, 256 threads, 4x4 per thread.
// AMODE: 0 = dense A, 1 = ef-gather [nf[src]|nf[dst]|rbf], 2 = ncat-gather [nf|aggr]
// EPI:   0 = bias+silu, 1 = bias, 2 = bias + residual add (res ptr)
template<int AMODE, int EPI>
__global__ __launch_bounds__(256) void gemm_kernel(
        const float* __restrict__ A, const float* __restrict__ nf,
        const int* __restrict__ dstl, const float* __restrict__ rbf,
        const float* __restrict__ aggr, const float* __restrict__ B,
        const float* __restrict__ bias, const float* __restrict__ res,
        float* __restrict__ C, int M, int Nn, int Kk) {
    __shared__ float As[16][64];
    __shared__ float Bs[16][64];
    const int t = threadIdx.x;
    const int r  = t & 63;          // A row in tile
    const int kq = t >> 6;          // 0..3 -> k-quad
    const int bk = t >> 4;          // 0..15 B row
    const int bc = (t & 15) * 4;    // B col quad
    const int ty = t >> 4, tx = t & 15;
    const int row0 = blockIdx.x * 64;
    const int col0 = blockIdx.y * 64;
    const int grow = row0 + r;
    int dstj = 0;
    if (AMODE == 1) dstj = dstl[grow];
    const int srci = (AMODE == 1) ? (grow / KN) : grow;
    float acc[4][4] = {};
    for (int k0 = 0; k0 < Kk; k0 += 16) {
        {
            const int c = k0 + kq*4;
            float4 av;
            if (AMODE == 0) {
                av = *reinterpret_cast<const float4*>(A + (size_t)grow*Kk + c);
            } else if (AMODE == 1) {
                if (c < NDIM)        av = *reinterpret_cast<const float4*>(nf + (size_t)srci*NDIM + c);
                else if (c < 2*NDIM) av = *reinterpret_cast<const float4*>(nf + (size_t)dstj*NDIM + (c - NDIM));
                else                 av = *reinterpret_cast<const float4*>(rbf + (size_t)grow*EDIM + (c - 2*NDIM));
            } else {
                if (c < NDIM) av = *reinterpret_cast<const float4*>(nf + (size_t)grow*NDIM + c);
                else          av = *reinterpret_cast<const float4*>(aggr + (size_t)grow*HDIM + (c - NDIM));
            }
            As[kq*4+0][r] = av.x; As[kq*4+1][r] = av.y; As[kq*4+2][r] = av.z; As[kq*4+3][r] = av.w;
        }
        {
            float4 bv = *reinterpret_cast<const float4*>(B + (size_t)(k0+bk)*Nn + col0 + bc);
            *reinterpret_cast<float4*>(&Bs[bk][bc]) = bv;
        }
        __syncthreads();
#pragma unroll
        for (int kk = 0; kk < 16; ++kk) {
            float4 a = *reinterpret_cast<const float4*>(&As[kk][ty*4]);
            float4 b = *reinterpret_cast<const float4*>(&Bs[kk][tx*4]);
            float ai[4] = {a.x,a.y,a.z,a.w};
            float bj[4] = {b.x,b.y,b.z,b.w};
#pragma unroll
            for (int ii = 0; ii < 4; ++ii)
#pragma unroll
                for (int jj = 0; jj < 4; ++jj)
                    acc[ii][jj] = fmaf(ai[ii], bj[jj], acc[ii][jj]);
        }
        __syncthreads();
    }
#pragma unroll
    for (int ii = 0; ii < 4; ++ii) {
        const int rr = row0 + ty*4 + ii;
#pragma unroll
        for (int jj = 0; jj < 4; ++jj) {
            const int cc = col0 + tx*4 + jj;
            float v = acc[ii][jj] + bias[cc];
            if (EPI == 0) v = siluf(v);
            if (EPI == 2) v += res[(size_t)rr*Nn + cc];
            C[(size_t)rr*Nn + cc] = v;
        }
    }
}

// aggr[j,:] = sum over incoming edges of msg[e,:]
__global__ void aggr_kernel(const float* __restrict__ msg, const int* __restrict__ ccnt,
                            const int* __restrict__ cedg, float* __restrict__ aggr) {
    const int j = blockIdx.x, c = threadIdx.x;   // 256 threads
    const int cnt = ccnt[j];
    float s = 0.0f;
    for (int q = 0; q < cnt; ++q) {
        int e = cedg[(size_t)j*MAXDEG + q];
        s += msg[(size_t)e*HDIM + c];
    }
    aggr[(size_t)j*HDIM + c] = s;
}

// w[e] = dot(t2[e,:128], cW2) + cb2 ; one wave per edge
__global__ void wdot_kernel(const float* __restrict__ t2, const float* __restrict__ cW2,
                            const float* __restrict__ cb2, float* __restrict__ w) {
    const int e = blockIdx.x*4 + (threadIdx.x >> 6);
    const int lane = threadIdx.x & 63;
    float v = t2[(size_t)e*128 + lane]      * cW2[lane]
            + t2[(size_t)e*128 + 64 + lane] * cW2[64 + lane];
    for (int off = 32; off > 0; off >>= 1) v += __shfl_xor(v, off, 64);
    if (lane == 0) w[e] = v + cb2[0];
}

// coords_new[j] = coords[j] + sum_e w[e] * normalize(coords[src_e] - coords[j])
__global__ void coords_kernel(const float* __restrict__ cold, const float* __restrict__ wv,
                              const int* __restrict__ ccnt, const int* __restrict__ cedg,
                              float* __restrict__ cnew) {
    int j = blockIdx.x*256 + threadIdx.x;
    if (j >= NA) return;
    float jx = cold[j*3], jy = cold[j*3+1], jz = cold[j*3+2];
    float dx = 0, dy = 0, dz = 0;
    int cnt = ccnt[j];
    for (int q = 0; q < cnt; ++q) {
        int e = cedg[(size_t)j*MAXDEG + q];
        int si = e / KN;
        float ax = cold[si*3]   - jx;
        float ay = cold[si*3+1] - jy;
        float az = cold[si*3+2] - jz;
        float inv = wv[e] / (sqrtf(ax*ax + ay*ay + az*az) + 1e-8f);
        dx += inv*ax; dy += inv*ay; dz += inv*az;
    }
    cnew[j*3]   = jx + dx;
    cnew[j*3+1] = jy + dy;
    cnew[j*3+2] = jz + dz;
}

__global__ void copyout_kernel(const float* __restrict__ nf, const float* __restrict__ coords,
                               float* __restrict__ out) {
    int idx = blockIdx.x*256 + threadIdx.x;
    if (idx < NA*NDIM) out[idx] = nf[idx];
    else if (idx < NA*NDIM + NA*3) out[idx] = coords[idx - NA*NDIM];
}

extern "C" void kernel_launch(void* const* d_in, const int* in_sizes, int n_in,
                              void* d_out, int out_size, void* d_ws, size_t ws_size,
                              hipStream_t stream) {
    const int*   atom_types = (const int*)  d_in[0];
    const float* frac       = (const float*)d_in[1];
    const float* lengths    = (const float*)d_in[2];
    const float* angles     = (const float*)d_in[3];
    const float* timesteps  = (const float*)d_in[4];
    const float* emb        = (const float*)d_in[5];
    const float* tW         = (const float*)d_in[6];
    const float* tb         = (const float*)d_in[7];
    const float* eW1        = (const float*)d_in[8];
    const float* eb1        = (const float*)d_in[9];
    const float* eW2        = (const float*)d_in[10];
    const float* eb2        = (const float*)d_in[11];
    const float* nW1        = (const float*)d_in[12];
    const float* nb1        = (const float*)d_in[13];
    const float* nW2        = (const float*)d_in[14];
    const float* nb2        = (const float*)d_in[15];
    const float* cW1        = (const float*)d_in[16];
    const float* cb1        = (const float*)d_in[17];
    const float* cW2        = (const float*)d_in[18];
    const float* cb2        = (const float*)d_in[19];

    char* p = (char*)d_ws;
    auto alloc = [&](size_t bytes) { char* q = p; p += (bytes + 255) & ~(size_t)255; return q; };
    float* sv   = (float*)alloc(81*4);
    float* c0   = (float*)alloc((size_t)NA*3*4);
    float* c1   = (float*)alloc((size_t)NA*3*4);
    float* nf   = (float*)alloc((size_t)NA*NDIM*4);
    int*   dstl = (int*)  alloc((size_t)NE*4);
    float* de   = (float*)alloc((size_t)NE*4);
    float* rbf  = (float*)alloc((size_t)NE*EDIM*4);
    int*   ccnt = (int*)  alloc((size_t)NA*4);
    int*   cedg = (int*)  alloc((size_t)NA*MAXDEG*4);
    float* aggr = (float*)alloc((size_t)NA*HDIM*4);
    float* t1   = (float*)alloc((size_t)NA*HDIM*4);
    float* h1   = (float*)alloc((size_t)NE*HDIM*4);
    float* msg  = (float*)alloc((size_t)NE*HDIM*4);
    float* wv   = (float*)alloc((size_t)NE*4);
    float* t2   = h1;  // h1 dead after gemm2; reuse for t2

    setup_kernel<<<8, 256, 0, stream>>>(frac, lengths, angles, c0, sv);
    knn_kernel<<<NA, 256, 0, stream>>>(c0, sv, dstl, de);
    rbf_kernel<<<(NE*EDIM)/256, 256, 0, stream>>>(de, rbf);
    csr_kernel<<<NA, 64, 0, stream>>>(dstl, ccnt, cedg);
    nf_init_kernel<<<NA, 128, 0, stream>>>(atom_types, timesteps, emb, tW, tb, nf);

    float* cin = c0; float* cout = c1;
    for (int l = 0; l < NLAYER; ++l) {
        const float* eW1l = eW1 + (size_t)l*(2*NDIM+EDIM)*HDIM;
        const float* eb1l = eb1 + (size_t)l*HDIM;
        const float* eW2l = eW2 + (size_t)l*HDIM*HDIM;
        const float* eb2l = eb2 + (size_t)l*HDIM;
        const float* nW1l = nW1 + (size_t)l*(NDIM+HDIM)*HDIM;
        const float* nb1l = nb1 + (size_t)l*HDIM;
        const float* nW2l = nW2 + (size_t)l*HDIM*NDIM;
        const float* nb2l = nb2 + (size_t)l*NDIM;
        const float* cW1l = cW1 + (size_t)l*HDIM*(HDIM/2);
        const float* cb1l = cb1 + (size_t)l*(HDIM/2);
        const float* cW2l = cW2 + (size_t)l*(HDIM/2);
        const float* cb2l = cb2 + (size_t)l;

        // h1 = silu(ef @ eW1 + eb1)
        gemm_kernel<1,0><<<dim3(NE/64, HDIM/64), 256, 0, stream>>>(
            nullptr, nf, dstl, rbf, nullptr, eW1l, eb1l, nullptr, h1, NE, HDIM, 2*NDIM+EDIM);
        // msg = silu(h1 @ eW2 + eb2)
        gemm_kernel<0,0><<<dim3(NE/64, HDIM/64), 256, 0, stream>>>(
            h1, nullptr, nullptr, nullptr, nullptr, eW2l, eb2l, nullptr, msg, NE, HDIM, HDIM);
        // aggr = segment_sum(msg, dst)
        aggr_kernel<<<NA, HDIM, 0, stream>>>(msg, ccnt, cedg, aggr);
        // t1 = silu([nf|aggr] @ nW1 + nb1)
        gemm_kernel<2,0><<<dim3(NA/64, HDIM/64), 256, 0, stream>>>(
            nullptr, nf, nullptr, nullptr, aggr, nW1l, nb1l, nullptr, t1, NA, HDIM, NDIM+HDIM);
        // nf = nf + t1 @ nW2 + nb2
        gemm_kernel<0,2><<<dim3(NA/64, NDIM/64), 256, 0, stream>>>(
            t1, nullptr, nullptr, nullptr, nullptr, nW2l, nb2l, nf, nf, NA, NDIM, HDIM);
        // t2 = silu(msg @ cW1 + cb1)
        gemm_kernel<0,0><<<dim3(NE/64, (HDIM/2)/64), 256, 0, stream>>>(
            msg, nullptr, nullptr, nullptr, nullptr, cW1l, cb1l, nullptr, t2, NE, HDIM/2, HDIM);
        // w = t2 @ cW2 + cb2
        wdot_kernel<<<NE/4, 256, 0, stream>>>(t2, cW2l, cb2l, wv);
        // coords update (ping-pong)
        coords_kernel<<<(NA+255)/256, 256, 0, stream>>>(cin, wv, ccnt, cedg, cout);
        float* tmp = cin; cin = cout; cout = tmp;
    }
    copyout_kernel<<<(NA*NDIM + NA*3)/256, 256, 0, stream>>>(nf, cin, (float*)d_out);
}

// Round 2
// 948.376 us; speedup vs baseline: 1.9461x; 1.9461x over previous
//
#include <hip/hip_runtime.h>
#include <math.h>

#define NA 2048          // atoms
#define KN 24            // neighbors per atom
#define NE (NA*KN)       // edges = 49152
#define NDIM 128         // node dim
#define EDIM 64          // rbf dim
#define HDIM 256         // hidden dim
#define NLAYER 4
#define MAXDEG 256       // cap on in-degree for CSR
#define KCAP 1024        // candidate buffer for knn
#define LDK 40           // LDS K-stride (bf16 elems): 32 + 8 pad -> 2-way bank alias (free)

typedef __attribute__((ext_vector_type(8))) short bf16x8;
typedef __attribute__((ext_vector_type(4))) float f32x4;

__device__ __forceinline__ float siluf(float x) { return x / (1.0f + expf(-x)); }
__device__ __forceinline__ ushort f2b(float x) {  // RNE float->bf16
    unsigned u = __float_as_uint(x);
    return (ushort)((u + 0x7fffu + ((u >> 16) & 1u)) >> 16);
}
__device__ __forceinline__ float b2f(ushort h) { return __uint_as_float(((unsigned)h) << 16); }

struct Lat { float lx, xy, xz, ly, yz, lz; };

__device__ __forceinline__ Lat make_lattice(const float* lengths, const float* angles) {
    const float deg = 0.017453292519943295f;
    float a = lengths[0], b = lengths[1], c = lengths[2];
    float al = angles[0]*deg, be = angles[1]*deg, ga = angles[2]*deg;
    Lat L;
    L.lx = a;
    L.xy = b * cosf(ga);
    L.xz = c * cosf(be);
    L.ly = b * sinf(ga);
    L.yz = (b*c*cosf(al) - L.xy*L.xz) / L.ly;
    L.lz = sqrtf(c*c - L.xz*L.xz - L.yz*L.yz);
    return L;
}

__global__ void setup_kernel(const float* __restrict__ frac, const float* __restrict__ lengths,
                             const float* __restrict__ angles, float* __restrict__ cart,
                             float* __restrict__ sv) {
    int i = blockIdx.x*blockDim.x + threadIdx.x;
    Lat L = make_lattice(lengths, angles);
    if (i < NA) {
        float f0 = frac[i*3], f1 = frac[i*3+1], f2 = frac[i*3+2];
        cart[i*3+0] = f0*L.lx + f1*L.xy + f2*L.xz;
        cart[i*3+1] = f1*L.ly + f2*L.yz;
        cart[i*3+2] = f2*L.lz;
    }
    if (i < 27) {
        float s0 = (float)(i/9 - 1), s1 = (float)((i/3)%3 - 1), s2 = (float)(i%3 - 1);
        sv[i*3+0] = s0*L.lx + s1*L.xy + s2*L.xz;
        sv[i*3+1] = s1*L.ly + s2*L.yz;
        sv[i*3+2] = s2*L.lz;
    }
}

// Per-atom top-24 neighbor search (matches jax.lax.top_k tie-breaking by flat idx).
__global__ __launch_bounds__(256) void knn_kernel(const float* __restrict__ cart,
        const float* __restrict__ sv, int* __restrict__ dstl, float* __restrict__ de) {
    __shared__ float scart[NA*3];
    __shared__ float ssv[81];
    __shared__ float sd[KCAP];
    __shared__ int   sf[KCAP];
    __shared__ unsigned long long rk[256];
    __shared__ int scnt;
    const int t = threadIdx.x;
    const int i = blockIdx.x;
    for (int q = t; q < NA*3; q += 256) scart[q] = cart[q];
    if (t < 81) ssv[t] = sv[t];
    __syncthreads();
    const float cx = scart[i*3], cy = scart[i*3+1], cz = scart[i*3+2];
    float R = 2.8f;
    int cnt = 0;
    for (int attempt = 0; attempt < 8; ++attempt) {
        if (t == 0) scnt = 0;
        __syncthreads();
        for (int f = t; f < 27*NA; f += 256) {
            const int s = f >> 11, j = f & (NA-1);
            const float px = scart[j*3]   + ssv[s*3];
            const float py = scart[j*3+1] + ssv[s*3+1];
            const float pz = scart[j*3+2] + ssv[s*3+2];
            const float dx = px-cx, dy = py-cy, dz = pz-cz;
            const float dist = sqrtf(fmaxf(dx*dx+dy*dy+dz*dz, 1e-12f));
            if (dist > 0.01f && dist < R) {
                int slot = atomicAdd(&scnt, 1);
                if (slot < KCAP) { sd[slot] = dist; sf[slot] = f; }
            }
        }
        __syncthreads();
        cnt = scnt < KCAP ? scnt : KCAP;
        if (cnt >= KN) break;
        R = fminf(R * 1.6f, 8.0f);
        __syncthreads();
    }
    for (int q = cnt + t; q < KCAP; q += 256) { sd[q] = INFINITY; sf[q] = 0; }
    __syncthreads();
    for (int k = 0; k < KN; ++k) {
        unsigned long long best = ~0ull;
        for (int q = t; q < KCAP; q += 256) {
            unsigned long long key = ((unsigned long long)__float_as_uint(sd[q]) << 26)
                                   | ((unsigned long long)(unsigned)sf[q] << 10) | (unsigned)q;
            best = best < key ? best : key;
        }
        rk[t] = best;
        __syncthreads();
        for (int off = 128; off > 0; off >>= 1) {
            if (t < off) { if (rk[t+off] < rk[t]) rk[t] = rk[t+off]; }
            __syncthreads();
        }
        if (t == 0) {
            int slot = (int)(rk[0] & 1023u);
            dstl[i*KN + k] = sf[slot] & (NA-1);
            de[i*KN + k]   = sd[slot];
            sd[slot] = INFINITY;
        }
        __syncthreads();
    }
}

__global__ void rbf_kernel(const float* __restrict__ de, ushort* __restrict__ rbf16) {
    int idx = blockIdx.x*256 + threadIdx.x;
    if (idx >= NE*EDIM) return;
    int e = idx >> 6, c = idx & 63;
    float d = de[e];
    float center = (8.0f/63.0f) * (float)c;
    float diff = d - center;
    float g = expf(diff*diff * -32.0f);
    float cv = 0.5f * (cosf(d * (float)(M_PI/8.0)) + 1.0f);
    rbf16[idx] = f2b(g * cv);
}

// CSR build: atomic scatter (counts deterministic) then per-node ascending sort (order deterministic).
__global__ void scatter_kernel(const int* __restrict__ dstl, int* __restrict__ ccnt,
                               int* __restrict__ cedg) {
    int e = blockIdx.x*256 + threadIdx.x;
    if (e >= NE) return;
    int j = dstl[e];
    int slot = atomicAdd(&ccnt[j], 1);
    if (slot < MAXDEG) cedg[(size_t)j*MAXDEG + slot] = e;
}

__global__ void csort_kernel(const int* __restrict__ ccnt, int* __restrict__ cedg) {
    int j = blockIdx.x*64 + threadIdx.x;
    if (j >= NA) return;
    int cnt = min(ccnt[j], MAXDEG);
    int* L = cedg + (size_t)j*MAXDEG;
    for (int a = 1; a < cnt; ++a) {
        int v = L[a]; int b = a - 1;
        while (b >= 0 && L[b] > v) { L[b+1] = L[b]; --b; }
        L[b+1] = v;
    }
}

__global__ void nf_init_kernel(const int* __restrict__ atom_types, const float* __restrict__ ts,
                               const float* __restrict__ emb, const float* __restrict__ tW,
                               const float* __restrict__ tb, float* __restrict__ nf) {
    int i = blockIdx.x, c = threadIdx.x;  // 128 threads
    float acc = emb[atom_types[i]*NDIM + c] + tb[c];
    for (int kk = 0; kk < 128; ++kk) acc += ts[i*128 + kk] * tW[kk*NDIM + c];
    nf[i*NDIM + c] = acc;
}

// weight prep: Wt[n][k] = bf16(W[k][n])
__global__ void wprep_kernel(const float* __restrict__ W, ushort* __restrict__ Wt, int Kk, int Nn) {
    int idx = blockIdx.x*256 + threadIdx.x;
    if (idx >= Kk*Nn) return;
    int n = idx / Kk, k = idx - n*Kk;
    Wt[idx] = f2b(W[(size_t)k*Nn + n]);
}

__global__ void cvt_kernel(const float* __restrict__ in, ushort* __restrict__ out, int n) {
    int i = blockIdx.x*256 + threadIdx.x;
    if (i < n) out[i] = f2b(in[i]);
}

// bf16 MFMA GEMM: C = bf16(silu(A @ Bt^T + bias)). 128x128 tile, BK=32, 4 waves (64x64 each).
// A row-major bf16 [M][Kk]; Bt row-major bf16 [Nn][Kk] (pre-transposed weights).
// AMODE: 0 = dense A, 1 = ef-gather [nf16[src] | nf16[dst] | rbf16] (Kk=320)
template<int AMODE>
__global__ __launch_bounds__(256) void bgemm_kernel(
        const ushort* __restrict__ A, const ushort* __restrict__ nf16,
        const int* __restrict__ dstl, const ushort* __restrict__ rbf16,
        const ushort* __restrict__ Bt, const float* __restrict__ bias,
        ushort* __restrict__ C, int M, int Nn, int Kk) {
    __shared__ alignas(16) ushort As[128*LDK];
    __shared__ alignas(16) ushort Bs[128*LDK];
    const int t = threadIdx.x;
    const int wave = t >> 6, lane = t & 63;
    const int row0 = blockIdx.x*128, col0 = blockIdx.y*128;
    const int wr = (wave >> 1) * 64, wc = (wave & 1) * 64;
    const int lr = lane & 15, lk = (lane >> 4) * 8;
    f32x4 acc[4][4] = {};
    for (int k0 = 0; k0 < Kk; k0 += 32) {
#pragma unroll
        for (int q = 0; q < 2; ++q) {
            const int id = t + q*256;        // 0..511
            const int r  = id >> 2;          // 0..127
            const int kc = (id & 3) * 8;     // 0,8,16,24
            const int kg = k0 + kc;
            uint4 av;
            if (AMODE == 0) {
                av = *reinterpret_cast<const uint4*>(A + (size_t)(row0+r)*Kk + kg);
            } else {
                const int e = row0 + r;
                const ushort* sp;
                if (kg < NDIM)        sp = nf16 + (size_t)(e/KN)*NDIM + kg;
                else if (kg < 2*NDIM) sp = nf16 + (size_t)dstl[e]*NDIM + (kg - NDIM);
                else                  sp = rbf16 + (size_t)e*EDIM + (kg - 2*NDIM);
                av = *reinterpret_cast<const uint4*>(sp);
            }
            *reinterpret_cast<uint4*>(&As[r*LDK + kc]) = av;
            uint4 bv = *reinterpret_cast<const uint4*>(Bt + (size_t)(col0+r)*Kk + kg);
            *reinterpret_cast<uint4*>(&Bs[r*LDK + kc]) = bv;
        }
        __syncthreads();
        bf16x8 af[4], bfr[4];
#pragma unroll
        for (int m = 0; m < 4; ++m)
            af[m] = *reinterpret_cast<const bf16x8*>(&As[(wr + m*16 + lr)*LDK + lk]);
#pragma unroll
        for (int n = 0; n < 4; ++n)
            bfr[n] = *reinterpret_cast<const bf16x8*>(&Bs[(wc + n*16 + lr)*LDK + lk]);
#pragma unroll
        for (int m = 0; m < 4; ++m)
#pragma unroll
            for (int n = 0; n < 4; ++n)
                acc[m][n] = __builtin_amdgcn_mfma_f32_16x16x32_bf16(af[m], bfr[n], acc[m][n], 0, 0, 0);
        __syncthreads();
    }
    // C/D layout: col = lane&15, row = (lane>>4)*4 + j   [m89-verified]
#pragma unroll
    for (int n = 0; n < 4; ++n) {
        const int cc = col0 + wc + n*16 + lr;
        const float bb = bias[cc];
#pragma unroll
        for (int m = 0; m < 4; ++m) {
#pragma unroll
            for (int j = 0; j < 4; ++j) {
                const int rr = row0 + wr + m*16 + (lane >> 4)*4 + j;
                float x = acc[m][n][j] + bb;
                x = siluf(x);
                C[(size_t)rr*Nn + cc] = f2b(x);
            }
        }
    }
}

// fp32 tiled GEMM for small node-side matmuls (M=2048).
// AMODE: 0 = dense A, 2 = ncat-gather [nf|aggr].  EPI: 0 = bias+silu, 2 = bias+residual.
template<int AMODE, int EPI>
__global__ __launch_bounds__(256) void gemm_kernel(
        const float* __restrict__ A, const float* __restrict__ nf,
        const float* __restrict__ aggr, const float* __restrict__ B,
        const float* __restrict__ bias, const float* __restrict__ res,
        float* __restrict__ C, int M, int Nn, int Kk) {
    __shared__ float As[16][64];
    __shared__ float Bs[16][64];
    const int t = threadIdx.x;
    const int r  = t & 63;
    const int kq = t >> 6;
    const int bk = t >> 4;
    const int bc = (t & 15) * 4;
    const int ty = t >> 4, tx = t & 15;
    const int row0 = blockIdx.x * 64;
    const int col0 = blockIdx.y * 64;
    const int grow = row0 + r;
    float acc[4][4] = {};
    for (int k0 = 0; k0 < Kk; k0 += 16) {
        {
            const int c = k0 + kq*4;
            float4 av;
            if (AMODE == 0) {
                av = *reinterpret_cast<const float4*>(A + (size_t)grow*Kk + c);
            } else {
                if (c < NDIM) av = *reinterpret_cast<const float4*>(nf + (size_t)grow*NDIM + c);
                else          av = *reinterpret_cast<const float4*>(aggr + (size_t)grow*HDIM + (c - NDIM));
            }
            As[kq*4+0][r] = av.x; As[kq*4+1][r] = av.y; As[kq*4+2][r] = av.z; As[kq*4+3][r] = av.w;
        }
        {
            float4 bv = *reinterpret_cast<const float4*>(B + (size_t)(k0+bk)*Nn + col0 + bc);
            *reinterpret_cast<float4*>(&Bs[bk][bc]) = bv;
        }
        __syncthreads();
#pragma unroll
        for (int kk = 0; kk < 16; ++kk) {
            float4 a = *reinterpret_cast<const float4*>(&As[kk][ty*4]);
            float4 b = *reinterpret_cast<const float4*>(&Bs[kk][tx*4]);
            float ai[4] = {a.x,a.y,a.z,a.w};
            float bj[4] = {b.x,b.y,b.z,b.w};
#pragma unroll
            for (int ii = 0; ii < 4; ++ii)
#pragma unroll
                for (int jj = 0; jj < 4; ++jj)
                    acc[ii][jj] = fmaf(ai[ii], bj[jj], acc[ii][jj]);
        }
        __syncthreads();
    }
#pragma unroll
    for (int ii = 0; ii < 4; ++ii) {
        const int rr = row0 + ty*4 + ii;
#pragma unroll
        for (int jj = 0; jj < 4; ++jj) {
            const int cc = col0 + tx*4 + jj;
            float v = acc[ii][jj] + bias[cc];
            if (EPI == 0) v = siluf(v);
            if (EPI == 2) v += res[(size_t)rr*Nn + cc];
            C[(size_t)rr*Nn + cc] = v;
        }
    }
}

// aggr[j,:] = sum over incoming edges of bf16 msg[e,:]
__global__ void aggr_kernel(const ushort* __restrict__ msg16, const int* __restrict__ ccnt,
                            const int* __restrict__ cedg, float* __restrict__ aggr) {
    const int j = blockIdx.x, c = threadIdx.x;   // 256 threads
    const int cnt = min(ccnt[j], MAXDEG);
    float s = 0.0f;
    for (int q = 0; q < cnt; ++q) {
        int e = cedg[(size_t)j*MAXDEG + q];
        s += b2f(msg16[(size_t)e*HDIM + c]);
    }
    aggr[(size_t)j*HDIM + c] = s;
}

// w[e] = dot(t2[e,:128], cW2) + cb2 ; one wave per edge (t2 in bf16)
__global__ void wdot_kernel(const ushort* __restrict__ t216, const float* __restrict__ cW2,
                            const float* __restrict__ cb2, float* __restrict__ w) {
    const int e = blockIdx.x*4 + (threadIdx.x >> 6);
    const int lane = threadIdx.x & 63;
    float v = b2f(t216[(size_t)e*128 + lane])      * cW2[lane]
            + b2f(t216[(size_t)e*128 + 64 + lane]) * cW2[64 + lane];
    for (int off = 32; off > 0; off >>= 1) v += __shfl_xor(v, off, 64);
    if (lane == 0) w[e] = v + cb2[0];
}

__global__ void coords_kernel(const float* __restrict__ cold, const float* __restrict__ wv,
                              const int* __restrict__ ccnt, const int* __restrict__ cedg,
                              float* __restrict__ cnew) {
    int j = blockIdx.x*256 + threadIdx.x;
    if (j >= NA) return;
    float jx = cold[j*3], jy = cold[j*3+1], jz = cold[j*3+2];
    float dx = 0, dy = 0, dz = 0;
    int cnt = min(ccnt[j], MAXDEG);
    for (int q = 0; q < cnt; ++q) {
        int e = cedg[(size_t)j*MAXDEG + q];
        int si = e / KN;
        float ax = cold[si*3]   - jx;
        float ay = cold[si*3+1] - jy;
        float az = cold[si*3+2] - jz;
        float inv = wv[e] / (sqrtf(ax*ax + ay*ay + az*az) + 1e-8f);
        dx += inv*ax; dy += inv*ay; dz += inv*az;
    }
    cnew[j*3]   = jx + dx;
    cnew[j*3+1] = jy + dy;
    cnew[j*3+2] = jz + dz;
}

__global__ void copyout_kernel(const float* __restrict__ nf, const float* __restrict__ coords,
                               float* __restrict__ out) {
    int idx = blockIdx.x*256 + threadIdx.x;
    if (idx < NA*NDIM) out[idx] = nf[idx];
    else if (idx < NA*NDIM + NA*3) out[idx] = coords[idx - NA*NDIM];
}

extern "C" void kernel_launch(void* const* d_in, const int* in_sizes, int n_in,
                              void* d_out, int out_size, void* d_ws, size_t ws_size,
                              hipStream_t stream) {
    const int*   atom_types = (const int*)  d_in[0];
    const float* frac       = (const float*)d_in[1];
    const float* lengths    = (const float*)d_in[2];
    const float* angles     = (const float*)d_in[3];
    const float* timesteps  = (const float*)d_in[4];
    const float* emb        = (const float*)d_in[5];
    const float* tW         = (const float*)d_in[6];
    const float* tb         = (const float*)d_in[7];
    const float* eW1        = (const float*)d_in[8];
    const float* eb1        = (const float*)d_in[9];
    const float* eW2        = (const float*)d_in[10];
    const float* eb2        = (const float*)d_in[11];
    const float* nW1        = (const float*)d_in[12];
    const float* nb1        = (const float*)d_in[13];
    const float* nW2        = (const float*)d_in[14];
    const float* nb2        = (const float*)d_in[15];
    const float* cW1        = (const float*)d_in[16];
    const float* cb1        = (const float*)d_in[17];
    const float* cW2        = (const float*)d_in[18];
    const float* cb2        = (const float*)d_in[19];

    char* p = (char*)d_ws;
    auto alloc = [&](size_t bytes) { char* q = p; p += (bytes + 255) & ~(size_t)255; return q; };
    float*  sv    = (float*) alloc(81*4);
    float*  c0    = (float*) alloc((size_t)NA*3*4);
    float*  c1    = (float*) alloc((size_t)NA*3*4);
    float*  nf    = (float*) alloc((size_t)NA*NDIM*4);
    int*    dstl  = (int*)   alloc((size_t)NE*4);
    float*  de    = (float*) alloc((size_t)NE*4);
    ushort* rbf16 = (ushort*)alloc((size_t)NE*EDIM*2);
    int*    ccnt  = (int*)   alloc((size_t)NA*4);
    int*    cedg  = (int*)   alloc((size_t)NA*MAXDEG*4);
    float*  aggr  = (float*) alloc((size_t)NA*HDIM*4);
    float*  t1    = (float*) alloc((size_t)NA*HDIM*4);
    float*  wv    = (float*) alloc((size_t)NE*4);
    ushort* nf16  = (ushort*)alloc((size_t)NA*NDIM*2);
    ushort* h116  = (ushort*)alloc((size_t)NE*HDIM*2);
    ushort* msg16 = (ushort*)alloc((size_t)NE*HDIM*2);
    ushort* t216  = (ushort*)alloc((size_t)NE*(HDIM/2)*2);
    ushort* eW1t  = (ushort*)alloc((size_t)NLAYER*(2*NDIM+EDIM)*HDIM*2);
    ushort* eW2t  = (ushort*)alloc((size_t)NLAYER*HDIM*HDIM*2);
    ushort* cW1t  = (ushort*)alloc((size_t)NLAYER*(HDIM/2)*HDIM*2);

    setup_kernel<<<8, 256, 0, stream>>>(frac, lengths, angles, c0, sv);
    knn_kernel<<<NA, 256, 0, stream>>>(c0, sv, dstl, de);
    rbf_kernel<<<(NE*EDIM)/256, 256, 0, stream>>>(de, rbf16);
    hipMemsetAsync(ccnt, 0, (size_t)NA*4, stream);
    scatter_kernel<<<NE/256, 256, 0, stream>>>(dstl, ccnt, cedg);
    csort_kernel<<<NA/64, 64, 0, stream>>>(ccnt, cedg);
    nf_init_kernel<<<NA, 128, 0, stream>>>(atom_types, timesteps, emb, tW, tb, nf);

    for (int l = 0; l < NLAYER; ++l) {
        wprep_kernel<<<((2*NDIM+EDIM)*HDIM + 255)/256, 256, 0, stream>>>(
            eW1 + (size_t)l*(2*NDIM+EDIM)*HDIM, eW1t + (size_t)l*(2*NDIM+EDIM)*HDIM, 2*NDIM+EDIM, HDIM);
        wprep_kernel<<<(HDIM*HDIM + 255)/256, 256, 0, stream>>>(
            eW2 + (size_t)l*HDIM*HDIM, eW2t + (size_t)l*HDIM*HDIM, HDIM, HDIM);
        wprep_kernel<<<(HDIM*(HDIM/2) + 255)/256, 256, 0, stream>>>(
            cW1 + (size_t)l*HDIM*(HDIM/2), cW1t + (size_t)l*HDIM*(HDIM/2), HDIM, HDIM/2);
    }

    float* cin = c0; float* cout = c1;
    for (int l = 0; l < NLAYER; ++l) {
        const float* eb1l = eb1 + (size_t)l*HDIM;
        const float* eb2l = eb2 + (size_t)l*HDIM;
        const float* nW1l = nW1 + (size_t)l*(NDIM+HDIM)*HDIM;
        const float* nb1l = nb1 + (size_t)l*HDIM;
        const float* nW2l = nW2 + (size_t)l*HDIM*NDIM;
        const float* nb2l = nb2 + (size_t)l*NDIM;
        const float* cb1l = cb1 + (size_t)l*(HDIM/2);
        const float* cW2l = cW2 + (size_t)l*(HDIM/2);
        const float* cb2l = cb2 + (size_t)l;

        cvt_kernel<<<(NA*NDIM)/256, 256, 0, stream>>>(nf, nf16, NA*NDIM);
        // h1 = silu(ef @ eW1 + eb1)  [bf16 MFMA, fused ef gather]
        bgemm_kernel<1><<<dim3(NE/128, HDIM/128), 256, 0, stream>>>(
            nullptr, nf16, dstl, rbf16, eW1t + (size_t)l*(2*NDIM+EDIM)*HDIM, eb1l,
            h116, NE, HDIM, 2*NDIM+EDIM);
        // msg = silu(h1 @ eW2 + eb2)
        bgemm_kernel<0><<<dim3(NE/128, HDIM/128), 256, 0, stream>>>(
            h116, nullptr, nullptr, nullptr, eW2t + (size_t)l*HDIM*HDIM, eb2l,
            msg16, NE, HDIM, HDIM);
        // aggr = segment_sum(msg, dst)
        aggr_kernel<<<NA, HDIM, 0, stream>>>(msg16, ccnt, cedg, aggr);
        // t1 = silu([nf|aggr] @ nW1 + nb1)   [fp32, M=2048]
        gemm_kernel<2,0><<<dim3(NA/64, HDIM/64), 256, 0, stream>>>(
            nullptr, nf, aggr, nW1l, nb1l, nullptr, t1, NA, HDIM, NDIM+HDIM);
        // nf = nf + t1 @ nW2 + nb2
        gemm_kernel<0,2><<<dim3(NA/64, NDIM/64), 256, 0, stream>>>(
            t1, nullptr, nullptr, nW2l, nb2l, nf, nf, NA, NDIM, HDIM);
        // t2 = silu(msg @ cW1 + cb1)
        bgemm_kernel<0><<<dim3(NE/128, (HDIM/2)/128), 256, 0, stream>>>(
            msg16, nullptr, nullptr, nullptr, cW1t + (size_t)l*(HDIM/2)*HDIM, cb1l,
            t216, NE, HDIM/2, HDIM);
        // w = t2 @ cW2 + cb2
        wdot_kernel<<<NE/4, 256, 0, stream>>>(t216, cW2l, cb2l, wv);
        // coords update
        coords_kernel<<<(NA+255)/256, 256, 0, stream>>>(cin, wv, ccnt, cedg, cout);
        float* tmp = cin; cin = cout; cout = tmp;
    }
    copyout_kernel<<<(NA*NDIM + NA*3)/256, 256, 0, stream>>>(nf, cin, (float*)d_out);
}

// Round 3
// 704.094 us; speedup vs baseline: 2.6213x; 1.3469x over previous
//
#include <hip/hip_runtime.h>
#include <math.h>

#define NA 2048          // atoms
#define KN 24            // neighbors per atom
#define NE (NA*KN)       // edges = 49152
#define NDIM 128         // node dim
#define EDIM 64          // rbf dim
#define HDIM 256         // hidden dim
#define NLAYER 4
#define MAXDEG 256       // cap on in-degree for CSR
#define KCAP 1024        // candidate buffer for knn

typedef __attribute__((ext_vector_type(8))) short bf16x8;
typedef __attribute__((ext_vector_type(4))) float f32x4;

__device__ __forceinline__ float siluf(float x) { return x / (1.0f + expf(-x)); }
__device__ __forceinline__ ushort f2b(float x) {  // RNE float->bf16
    unsigned u = __float_as_uint(x);
    return (ushort)((u + 0x7fffu + ((u >> 16) & 1u)) >> 16);
}
__device__ __forceinline__ float b2f(ushort h) { return __uint_as_float(((unsigned)h) << 16); }

// async global->LDS, 16B per lane. LDS dest = uniform base + lane*16 (linear).
__device__ __forceinline__ void gl_lds(const void* g, void* lds) {
    __builtin_amdgcn_global_load_lds(
        (const __attribute__((address_space(1))) unsigned int*)g,
        (__attribute__((address_space(3))) unsigned int*)lds, 16, 0, 0);
}

struct Lat { float lx, xy, xz, ly, yz, lz; };

__device__ __forceinline__ Lat make_lattice(const float* lengths, const float* angles) {
    const float deg = 0.017453292519943295f;
    float a = lengths[0], b = lengths[1], c = lengths[2];
    float al = angles[0]*deg, be = angles[1]*deg, ga = angles[2]*deg;
    Lat L;
    L.lx = a;
    L.xy = b * cosf(ga);
    L.xz = c * cosf(be);
    L.ly = b * sinf(ga);
    L.yz = (b*c*cosf(al) - L.xy*L.xz) / L.ly;
    L.lz = sqrtf(c*c - L.xz*L.xz - L.yz*L.yz);
    return L;
}

__global__ void setup_kernel(const float* __restrict__ frac, const float* __restrict__ lengths,
                             const float* __restrict__ angles, float* __restrict__ cart,
                             float* __restrict__ sv) {
    int i = blockIdx.x*blockDim.x + threadIdx.x;
    Lat L = make_lattice(lengths, angles);
    if (i < NA) {
        float f0 = frac[i*3], f1 = frac[i*3+1], f2 = frac[i*3+2];
        cart[i*3+0] = f0*L.lx + f1*L.xy + f2*L.xz;
        cart[i*3+1] = f1*L.ly + f2*L.yz;
        cart[i*3+2] = f2*L.lz;
    }
    if (i < 27) {
        float s0 = (float)(i/9 - 1), s1 = (float)((i/3)%3 - 1), s2 = (float)(i%3 - 1);
        sv[i*3+0] = s0*L.lx + s1*L.xy + s2*L.xz;
        sv[i*3+1] = s1*L.ly + s2*L.yz;
        sv[i*3+2] = s2*L.lz;
    }
}

// AABB of cart points (single block)
__global__ void aabb_kernel(const float* __restrict__ cart, float* __restrict__ aabb) {
    __shared__ float red[6][4];
    const int t = threadIdx.x;  // 256
    float mn[3] = {1e30f,1e30f,1e30f}, mx[3] = {-1e30f,-1e30f,-1e30f};
    for (int j = t; j < NA; j += 256) {
        for (int a = 0; a < 3; ++a) {
            float v = cart[j*3+a];
            mn[a] = fminf(mn[a], v); mx[a] = fmaxf(mx[a], v);
        }
    }
    for (int off = 32; off > 0; off >>= 1) {
        for (int a = 0; a < 3; ++a) {
            mn[a] = fminf(mn[a], __shfl_xor(mn[a], off, 64));
            mx[a] = fmaxf(mx[a], __shfl_xor(mx[a], off, 64));
        }
    }
    const int wv = t >> 6, ln = t & 63;
    if (ln == 0) for (int a = 0; a < 3; ++a) { red[a][wv] = mn[a]; red[3+a][wv] = mx[a]; }
    __syncthreads();
    if (t == 0) {
        for (int a = 0; a < 3; ++a) {
            float lo = fminf(fminf(red[a][0], red[a][1]), fminf(red[a][2], red[a][3]));
            float hi = fmaxf(fmaxf(red[3+a][0], red[3+a][1]), fmaxf(red[3+a][2], red[3+a][3]));
            aabb[a*2] = lo; aabb[a*2+1] = hi;
        }
    }
}

// Per-atom top-24: AABB shift prune + squared-distance collect + wave-level extraction.
// Matches jax.lax.top_k tie-break (sort key = (dist, flat idx f = s*NA + j)).
__global__ __launch_bounds__(256) void knn_kernel(const float* __restrict__ cart,
        const float* __restrict__ sv, const float* __restrict__ aabb,
        int* __restrict__ dstl, float* __restrict__ de) {
    __shared__ float sx[NA], sy[NA], sz[NA];
    __shared__ float sd2[KCAP];
    __shared__ int   sf[KCAP];
    __shared__ float stx[27], sty[27], stz[27];
    __shared__ int   ssi[27];
    __shared__ int   nsh, scnt;
    const int t = threadIdx.x, i = blockIdx.x;
    for (int j = t; j < NA; j += 256) {
        sx[j] = cart[j*3]; sy[j] = cart[j*3+1]; sz[j] = cart[j*3+2];
    }
    __syncthreads();
    const float cx = sx[i], cy = sy[i], cz = sz[i];
    const float lox = aabb[0], hix = aabb[1], loy = aabb[2], hiy = aabb[3],
                loz = aabb[4], hiz = aabb[5];
    float R = 2.8f;
    int cnt = 0;
    for (int attempt = 0; attempt < 8; ++attempt) {
        const float R2 = R * R;
        if (t == 0) { nsh = 0; scnt = 0; }
        __syncthreads();
        if (t < 27) {   // per-shift prune: min dist from T=cart_i - sv_s to AABB(cart)
            float tx = cx - sv[t*3], ty = cy - sv[t*3+1], tz = cz - sv[t*3+2];
            float dx = fmaxf(fmaxf(lox-tx, tx-hix), 0.0f);
            float dy = fmaxf(fmaxf(loy-ty, ty-hiy), 0.0f);
            float dz = fmaxf(fmaxf(loz-tz, tz-hiz), 0.0f);
            if (dx*dx + dy*dy + dz*dz <= R2) {
                int s = atomicAdd(&nsh, 1);
                stx[s] = tx; sty[s] = ty; stz[s] = tz; ssi[s] = t;
            }
        }
        __syncthreads();
        const int ns = nsh;
        for (int q = 0; q < ns; ++q) {
            const float tx = stx[q], ty = sty[q], tz = stz[q];
            const int fb = ssi[q] << 11;     // s * NA
            for (int j = t; j < NA; j += 256) {
                float dx = sx[j]-tx, dy = sy[j]-ty, dz = sz[j]-tz;
                float d2 = fmaf(dx, dx, fmaf(dy, dy, dz*dz));
                if (d2 < R2 && d2 > 1e-4f) {
                    int slot = atomicAdd(&scnt, 1);
                    if (slot < KCAP) { sd2[slot] = d2; sf[slot] = fb + j; }
                }
            }
        }
        __syncthreads();
        cnt = min(scnt, KCAP);
        if (cnt >= KN) break;
        R = fminf(R * 1.6f, 8.0f);
        __syncthreads();
    }
    if (t < 64) {   // single-wave extraction: 24 rounds of shfl argmin, no barriers
        for (int k = 0; k < KN; ++k) {
            unsigned long long best = ~0ull;
            for (int q = t; q < cnt; q += 64) {
                unsigned long long key = ((unsigned long long)__float_as_uint(sd2[q]) << 26)
                                       | ((unsigned long long)(unsigned)sf[q] << 10) | (unsigned)q;
                best = best < key ? best : key;
            }
            for (int off = 32; off > 0; off >>= 1) {
                unsigned long long o = __shfl_xor(best, off, 64);
                best = best < o ? best : o;
            }
            if (t == 0) {
                int slot = (int)(best & 1023u);
                dstl[i*KN + k] = sf[slot] & (NA-1);
                de[i*KN + k]   = sqrtf(sd2[slot]);
                sd2[slot] = INFINITY;
            }
        }
    }
}

__global__ void rbf_kernel(const float* __restrict__ de, ushort* __restrict__ rbf16) {
    int idx = blockIdx.x*256 + threadIdx.x;
    if (idx >= NE*EDIM) return;
    int e = idx >> 6, c = idx & 63;
    float d = de[e];
    float center = (8.0f/63.0f) * (float)c;
    float diff = d - center;
    float g = expf(diff*diff * -32.0f);
    float cv = 0.5f * (cosf(d * (float)(M_PI/8.0)) + 1.0f);
    rbf16[idx] = f2b(g * cv);
}

// CSR build: atomic scatter (counts deterministic) then per-node ascending sort.
__global__ void scatter_kernel(const int* __restrict__ dstl, int* __restrict__ ccnt,
                               int* __restrict__ cedg) {
    int e = blockIdx.x*256 + threadIdx.x;
    if (e >= NE) return;
    int j = dstl[e];
    int slot = atomicAdd(&ccnt[j], 1);
    if (slot < MAXDEG) cedg[(size_t)j*MAXDEG + slot] = e;
}

__global__ void csort_kernel(const int* __restrict__ ccnt, int* __restrict__ cedg) {
    int j = blockIdx.x*64 + threadIdx.x;
    if (j >= NA) return;
    int cnt = min(ccnt[j], MAXDEG);
    int* L = cedg + (size_t)j*MAXDEG;
    for (int a = 1; a < cnt; ++a) {
        int v = L[a]; int b = a - 1;
        while (b >= 0 && L[b] > v) { L[b+1] = L[b]; --b; }
        L[b+1] = v;
    }
}

__global__ void nf_init_kernel(const int* __restrict__ atom_types, const float* __restrict__ ts,
                               const float* __restrict__ emb, const float* __restrict__ tW,
                               const float* __restrict__ tb, float* __restrict__ nf) {
    int i = blockIdx.x, c = threadIdx.x;  // 128 threads
    float acc = emb[atom_types[i]*NDIM + c] + tb[c];
    for (int kk = 0; kk < 128; ++kk) acc += ts[i*128 + kk] * tW[kk*NDIM + c];
    nf[i*NDIM + c] = acc;
}

// weight prep over all layers: Wt[l][n][k] = bf16(W[l][k][n])
__global__ void wprep_kernel(const float* __restrict__ W, ushort* __restrict__ Wt,
                             int Kk, int Nn) {
    int idx = blockIdx.x*256 + threadIdx.x;
    int per = Kk*Nn;
    if (idx >= NLAYER*per) return;
    int l = idx / per, rem = idx - l*per;
    int n = rem / Kk, k = rem - n*Kk;
    Wt[idx] = f2b(W[(size_t)l*per + (size_t)k*Nn + n]);
}

__global__ void cvt_kernel(const float* __restrict__ in, ushort* __restrict__ out, int n) {
    int i = blockIdx.x*256 + threadIdx.x;
    if (i < n) out[i] = f2b(in[i]);
}

// bf16 MFMA GEMM, 128x128 tile, BK=32, 4 waves (64x64 each).
// Staging: global_load_lds dwordx4, linear LDS [128][32], chunk-XOR g = c ^ ((r>>1)&3)
// pre-applied on the per-lane GLOBAL source; ds_read applies the same XOR (conflict-free).
// AMODE: 0 dense A | 1 ef-gather [nf16[src]|nf16[dst]|rbf16] | 2 ncat [nf16|aggr16]
// EPI:   0 bias+silu -> bf16 | 2 bias+res(fp32) -> fp32 Cf AND bf16 C16
template<int AMODE, int EPI>
__global__ __launch_bounds__(256) void bgemm_kernel(
        const ushort* __restrict__ A, const ushort* __restrict__ nf16,
        const int* __restrict__ dstl, const ushort* __restrict__ rbf16,
        const ushort* __restrict__ aggr16, const ushort* __restrict__ Bt,
        const float* __restrict__ bias, const float* __restrict__ res,
        float* __restrict__ Cf, ushort* __restrict__ C16, int M, int Nn, int Kk) {
    __shared__ alignas(16) ushort As[128*32];
    __shared__ alignas(16) ushort Bs[128*32];
    __shared__ int sdst[128];
    const int t = threadIdx.x;
    const int wave = t >> 6, lane = t & 63;
    const int row0 = blockIdx.x*128, col0 = blockIdx.y*128;
    if (AMODE == 1) {
        if (t < 128) sdst[t] = dstl[row0 + t];
        __syncthreads();
    }
    const bool stA = wave < 2;
    const int wr = (wave >> 1)*64, wc = (wave & 1)*64;
    const int lr = lane & 15, g0 = lane >> 4;
    f32x4 acc[4][4] = {};
    for (int k0 = 0; k0 < Kk; k0 += 32) {
#pragma unroll
        for (int q = 0; q < 4; ++q) {
            const int r = (wave & 1)*64 + q*16 + (lane >> 2);   // tile row this lane loads
            const int g = (lane & 3) ^ ((r >> 1) & 3);          // source chunk (pre-swizzle)
            const int kg = k0 + g*8;
            const int ldsbase = ((wave & 1)*64 + q*16) * 32;
            if (stA) {
                const ushort* gp;
                if (AMODE == 0) {
                    gp = A + (size_t)(row0 + r)*Kk + kg;
                } else if (AMODE == 1) {
                    const int e = row0 + r;
                    if (kg < NDIM)        gp = nf16 + (size_t)(e/KN)*NDIM + kg;
                    else if (kg < 2*NDIM) gp = nf16 + (size_t)sdst[r]*NDIM + (kg - NDIM);
                    else                  gp = rbf16 + (size_t)e*EDIM + (kg - 2*NDIM);
                } else {
                    const int e = row0 + r;
                    if (kg < NDIM) gp = nf16 + (size_t)e*NDIM + kg;
                    else           gp = aggr16 + (size_t)e*HDIM + (kg - NDIM);
                }
                gl_lds(gp, &As[ldsbase]);
            } else {
                gl_lds(Bt + (size_t)(col0 + r)*Kk + kg, &Bs[ldsbase]);
            }
        }
        __syncthreads();
        bf16x8 af[4], bfr[4];
#pragma unroll
        for (int m = 0; m < 4; ++m) {
            const int rA = wr + m*16 + lr;
            af[m] = *reinterpret_cast<const bf16x8*>(&As[rA*32 + ((g0 ^ ((rA>>1)&3)))*8]);
        }
#pragma unroll
        for (int n = 0; n < 4; ++n) {
            const int rB = wc + n*16 + lr;
            bfr[n] = *reinterpret_cast<const bf16x8*>(&Bs[rB*32 + ((g0 ^ ((rB>>1)&3)))*8]);
        }
#pragma unroll
        for (int m = 0; m < 4; ++m)
#pragma unroll
            for (int n = 0; n < 4; ++n)
                acc[m][n] = __builtin_amdgcn_mfma_f32_16x16x32_bf16(af[m], bfr[n], acc[m][n], 0, 0, 0);
        __syncthreads();
    }
    // C/D layout: col = lane&15, row = (lane>>4)*4 + j
#pragma unroll
    for (int n = 0; n < 4; ++n) {
        const int cc = col0 + wc + n*16 + lr;
        const float bb = bias[cc];
#pragma unroll
        for (int m = 0; m < 4; ++m) {
#pragma unroll
            for (int j = 0; j < 4; ++j) {
                const int rr = row0 + wr + m*16 + (lane >> 4)*4 + j;
                float x = acc[m][n][j] + bb;
                if (EPI == 0) {
                    C16[(size_t)rr*Nn + cc] = f2b(siluf(x));
                } else {
                    x += res[(size_t)rr*Nn + cc];
                    Cf[(size_t)rr*Nn + cc] = x;
                    C16[(size_t)rr*Nn + cc] = f2b(x);
                }
            }
        }
    }
}

// aggr16[j,:] = bf16( sum over incoming edges of msg[e,:] )
__global__ void aggr_kernel(const ushort* __restrict__ msg16, const int* __restrict__ ccnt,
                            const int* __restrict__ cedg, ushort* __restrict__ aggr16) {
    const int j = blockIdx.x, c = threadIdx.x;   // 256 threads
    const int cnt = min(ccnt[j], MAXDEG);
    float s = 0.0f;
    for (int q = 0; q < cnt; ++q) {
        int e = cedg[(size_t)j*MAXDEG + q];
        s += b2f(msg16[(size_t)e*HDIM + c]);
    }
    aggr16[(size_t)j*HDIM + c] = f2b(s);
}

// w[e] = dot(t2[e,:128], cW2) + cb2 ; one wave per edge (t2 in bf16)
__global__ void wdot_kernel(const ushort* __restrict__ t216, const float* __restrict__ cW2,
                            const float* __restrict__ cb2, float* __restrict__ w) {
    const int e = blockIdx.x*4 + (threadIdx.x >> 6);
    const int lane = threadIdx.x & 63;
    float v = b2f(t216[(size_t)e*128 + lane])      * cW2[lane]
            + b2f(t216[(size_t)e*128 + 64 + lane]) * cW2[64 + lane];
    for (int off = 32; off > 0; off >>= 1) v += __shfl_xor(v, off, 64);
    if (lane == 0) w[e] = v + cb2[0];
}

__global__ void coords_kernel(const float* __restrict__ cold, const float* __restrict__ wv,
                              const int* __restrict__ ccnt, const int* __restrict__ cedg,
                              float* __restrict__ cnew) {
    int j = blockIdx.x*256 + threadIdx.x;
    if (j >= NA) return;
    float jx = cold[j*3], jy = cold[j*3+1], jz = cold[j*3+2];
    float dx = 0, dy = 0, dz = 0;
    int cnt = min(ccnt[j], MAXDEG);
    for (int q = 0; q < cnt; ++q) {
        int e = cedg[(size_t)j*MAXDEG + q];
        int si = e / KN;
        float ax = cold[si*3]   - jx;
        float ay = cold[si*3+1] - jy;
        float az = cold[si*3+2] - jz;
        float inv = wv[e] / (sqrtf(ax*ax + ay*ay + az*az) + 1e-8f);
        dx += inv*ax; dy += inv*ay; dz += inv*az;
    }
    cnew[j*3]   = jx + dx;
    cnew[j*3+1] = jy + dy;
    cnew[j*3+2] = jz + dz;
}

__global__ void copyout_kernel(const float* __restrict__ nf, const float* __restrict__ coords,
                               float* __restrict__ out) {
    int idx = blockIdx.x*256 + threadIdx.x;
    if (idx < NA*NDIM) out[idx] = nf[idx];
    else if (idx < NA*NDIM + NA*3) out[idx] = coords[idx - NA*NDIM];
}

extern "C" void kernel_launch(void* const* d_in, const int* in_sizes, int n_in,
                              void* d_out, int out_size, void* d_ws, size_t ws_size,
                              hipStream_t stream) {
    const int*   atom_types = (const int*)  d_in[0];
    const float* frac       = (const float*)d_in[1];
    const float* lengths    = (const float*)d_in[2];
    const float* angles     = (const float*)d_in[3];
    const float* timesteps  = (const float*)d_in[4];
    const float* emb        = (const float*)d_in[5];
    const float* tW         = (const float*)d_in[6];
    const float* tb         = (const float*)d_in[7];
    const float* eW1        = (const float*)d_in[8];
    const float* eb1        = (const float*)d_in[9];
    const float* eW2        = (const float*)d_in[10];
    const float* eb2        = (const float*)d_in[11];
    const float* nW1        = (const float*)d_in[12];
    const float* nb1        = (const float*)d_in[13];
    const float* nW2        = (const float*)d_in[14];
    const float* nb2        = (const float*)d_in[15];
    const float* cW1        = (const float*)d_in[16];
    const float* cb1        = (const float*)d_in[17];
    const float* cW2        = (const float*)d_in[18];
    const float* cb2        = (const float*)d_in[19];

    char* p = (char*)d_ws;
    auto alloc = [&](size_t bytes) { char* q = p; p += (bytes + 255) & ~(size_t)255; return q; };
    float*  sv    = (float*) alloc(81*4);
    float*  aabb  = (float*) alloc(6*4);
    float*  c0    = (float*) alloc((size_t)NA*3*4);
    float*  c1    = (float*) alloc((size_t)NA*3*4);
    float*  nf    = (float*) alloc((size_t)NA*NDIM*4);
    int*    dstl  = (int*)   alloc((size_t)NE*4);
    float*  de    = (float*) alloc((size_t)NE*4);
    ushort* rbf16 = (ushort*)alloc((size_t)NE*EDIM*2);
    int*    ccnt  = (int*)   alloc((size_t)NA*4);
    int*    cedg  = (int*)   alloc((size_t)NA*MAXDEG*4);
    ushort* aggr16= (ushort*)alloc((size_t)NA*HDIM*2);
    ushort* t116  = (ushort*)alloc((size_t)NA*HDIM*2);
    float*  wv    = (float*) alloc((size_t)NE*4);
    ushort* nf16  = (ushort*)alloc((size_t)NA*NDIM*2);
    ushort* h116  = (ushort*)alloc((size_t)NE*HDIM*2);
    ushort* msg16 = (ushort*)alloc((size_t)NE*HDIM*2);
    ushort* t216  = (ushort*)alloc((size_t)NE*(HDIM/2)*2);
    ushort* eW1t  = (ushort*)alloc((size_t)NLAYER*(2*NDIM+EDIM)*HDIM*2);
    ushort* eW2t  = (ushort*)alloc((size_t)NLAYER*HDIM*HDIM*2);
    ushort* cW1t  = (ushort*)alloc((size_t)NLAYER*(HDIM/2)*HDIM*2);
    ushort* nW1t  = (ushort*)alloc((size_t)NLAYER*(NDIM+HDIM)*HDIM*2);
    ushort* nW2t  = (ushort*)alloc((size_t)NLAYER*HDIM*NDIM*2);

    setup_kernel<<<8, 256, 0, stream>>>(frac, lengths, angles, c0, sv);
    aabb_kernel<<<1, 256, 0, stream>>>(c0, aabb);
    knn_kernel<<<NA, 256, 0, stream>>>(c0, sv, aabb, dstl, de);
    rbf_kernel<<<(NE*EDIM)/256, 256, 0, stream>>>(de, rbf16);
    hipMemsetAsync(ccnt, 0, (size_t)NA*4, stream);
    scatter_kernel<<<NE/256, 256, 0, stream>>>(dstl, ccnt, cedg);
    csort_kernel<<<NA/64, 64, 0, stream>>>(ccnt, cedg);
    nf_init_kernel<<<NA, 128, 0, stream>>>(atom_types, timesteps, emb, tW, tb, nf);
    cvt_kernel<<<(NA*NDIM)/256, 256, 0, stream>>>(nf, nf16, NA*NDIM);

    wprep_kernel<<<NLAYER*(2*NDIM+EDIM)*HDIM/256, 256, 0, stream>>>(eW1, eW1t, 2*NDIM+EDIM, HDIM);
    wprep_kernel<<<NLAYER*HDIM*HDIM/256, 256, 0, stream>>>(eW2, eW2t, HDIM, HDIM);
    wprep_kernel<<<NLAYER*HDIM*(HDIM/2)/256, 256, 0, stream>>>(cW1, cW1t, HDIM, HDIM/2);
    wprep_kernel<<<NLAYER*(NDIM+HDIM)*HDIM/256, 256, 0, stream>>>(nW1, nW1t, NDIM+HDIM, HDIM);
    wprep_kernel<<<NLAYER*HDIM*NDIM/256, 256, 0, stream>>>(nW2, nW2t, HDIM, NDIM);

    float* cin = c0; float* cout = c1;
    for (int l = 0; l < NLAYER; ++l) {
        const float* eb1l = eb1 + (size_t)l*HDIM;
        const float* eb2l = eb2 + (size_t)l*HDIM;
        const float* nb1l = nb1 + (size_t)l*HDIM;
        const float* nb2l = nb2 + (size_t)l*NDIM;
        const float* cb1l = cb1 + (size_t)l*(HDIM/2);
        const float* cW2l = cW2 + (size_t)l*(HDIM/2);
        const float* cb2l = cb2 + (size_t)l;

        // h1 = silu(ef @ eW1 + eb1)  [gather A]
        bgemm_kernel<1,0><<<dim3(NE/128, HDIM/128), 256, 0, stream>>>(
            nullptr, nf16, dstl, rbf16, nullptr, eW1t + (size_t)l*(2*NDIM+EDIM)*HDIM, eb1l,
            nullptr, nullptr, h116, NE, HDIM, 2*NDIM+EDIM);
        // msg = silu(h1 @ eW2 + eb2)
        bgemm_kernel<0,0><<<dim3(NE/128, HDIM/128), 256, 0, stream>>>(
            h116, nullptr, nullptr, nullptr, nullptr, eW2t + (size_t)l*HDIM*HDIM, eb2l,
            nullptr, nullptr, msg16, NE, HDIM, HDIM);
        // aggr = segment_sum(msg, dst)
        aggr_kernel<<<NA, HDIM, 0, stream>>>(msg16, ccnt, cedg, aggr16);
        // t1 = silu([nf|aggr] @ nW1 + nb1)
        bgemm_kernel<2,0><<<dim3(NA/128, HDIM/128), 256, 0, stream>>>(
            nullptr, nf16, nullptr, nullptr, aggr16, nW1t + (size_t)l*(NDIM+HDIM)*HDIM, nb1l,
            nullptr, nullptr, t116, NA, HDIM, NDIM+HDIM);
        // nf = nf + t1 @ nW2 + nb2   (writes fp32 nf AND bf16 nf16)
        bgemm_kernel<0,2><<<dim3(NA/128, NDIM/128), 256, 0, stream>>>(
            t116, nullptr, nullptr, nullptr, nullptr, nW2t + (size_t)l*HDIM*NDIM, nb2l,
            nf, nf, nf16, NA, NDIM, HDIM);
        // t2 = silu(msg @ cW1 + cb1)
        bgemm_kernel<0,0><<<dim3(NE/128, (HDIM/2)/128), 256, 0, stream>>>(
            msg16, nullptr, nullptr, nullptr, nullptr, cW1t + (size_t)l*(HDIM/2)*HDIM, cb1l,
            nullptr, nullptr, t216, NE, HDIM/2, HDIM);
        // w = t2 @ cW2 + cb2
        wdot_kernel<<<NE/4, 256, 0, stream>>>(t216, cW2l, cb2l, wv);
        // coords update
        coords_kernel<<<(NA+255)/256, 256, 0, stream>>>(cin, wv, ccnt, cedg, cout);
        float* tmp = cin; cin = cout; cout = tmp;
    }
    copyout_kernel<<<(NA*NDIM + NA*3)/256, 256, 0, stream>>>(nf, cin, (float*)d_out);
}

// Round 4
// 526.223 us; speedup vs baseline: 3.5073x; 1.3380x over previous
//
#include <hip/hip_runtime.h>
#include <math.h>

#define NA 2048          // atoms
#define KN 24            // neighbors per atom
#define NE (NA*KN)       // edges = 49152
#define NDIM 128         // node dim
#define EDIM 64          // rbf dim
#define HDIM 256         // hidden dim
#define NLAYER 4
#define MAXDEG 256       // cap on in-degree for CSR
#define KCAP 1024        // candidate buffer for knn

typedef __attribute__((ext_vector_type(8))) short bf16x8;
typedef __attribute__((ext_vector_type(4))) float f32x4;

__device__ __forceinline__ float siluf(float x) { return x / (1.0f + expf(-x)); }
__device__ __forceinline__ ushort f2b(float x) {  // RNE float->bf16
    unsigned u = __float_as_uint(x);
    return (ushort)((u + 0x7fffu + ((u >> 16) & 1u)) >> 16);
}
__device__ __forceinline__ float b2f(ushort h) { return __uint_as_float(((unsigned)h) << 16); }

// async global->LDS, 16B per lane. LDS dest = uniform base + lane*16 (linear).
__device__ __forceinline__ void gl_lds(const void* g, void* lds) {
    __builtin_amdgcn_global_load_lds(
        (const __attribute__((address_space(1))) unsigned int*)g,
        (__attribute__((address_space(3))) unsigned int*)lds, 16, 0, 0);
}

struct Lat { float lx, xy, xz, ly, yz, lz; };

__device__ __forceinline__ Lat make_lattice(const float* lengths, const float* angles) {
    const float deg = 0.017453292519943295f;
    float a = lengths[0], b = lengths[1], c = lengths[2];
    float al = angles[0]*deg, be = angles[1]*deg, ga = angles[2]*deg;
    Lat L;
    L.lx = a;
    L.xy = b * cosf(ga);
    L.xz = c * cosf(be);
    L.ly = b * sinf(ga);
    L.yz = (b*c*cosf(al) - L.xy*L.xz) / L.ly;
    L.lz = sqrtf(c*c - L.xz*L.xz - L.yz*L.yz);
    return L;
}

__global__ void setup_kernel(const float* __restrict__ frac, const float* __restrict__ lengths,
                             const float* __restrict__ angles, float* __restrict__ cart,
                             float* __restrict__ sv) {
    int i = blockIdx.x*blockDim.x + threadIdx.x;
    Lat L = make_lattice(lengths, angles);
    if (i < NA) {
        float f0 = frac[i*3], f1 = frac[i*3+1], f2 = frac[i*3+2];
        cart[i*3+0] = f0*L.lx + f1*L.xy + f2*L.xz;
        cart[i*3+1] = f1*L.ly + f2*L.yz;
        cart[i*3+2] = f2*L.lz;
    }
    if (i < 27) {
        float s0 = (float)(i/9 - 1), s1 = (float)((i/3)%3 - 1), s2 = (float)(i%3 - 1);
        sv[i*3+0] = s0*L.lx + s1*L.xy + s2*L.xz;
        sv[i*3+1] = s1*L.ly + s2*L.yz;
        sv[i*3+2] = s2*L.lz;
    }
}

// AABB of cart points (single block)
__global__ void aabb_kernel(const float* __restrict__ cart, float* __restrict__ aabb) {
    __shared__ float red[6][4];
    const int t = threadIdx.x;  // 256
    float mn[3] = {1e30f,1e30f,1e30f}, mx[3] = {-1e30f,-1e30f,-1e30f};
    for (int j = t; j < NA; j += 256) {
        for (int a = 0; a < 3; ++a) {
            float v = cart[j*3+a];
            mn[a] = fminf(mn[a], v); mx[a] = fmaxf(mx[a], v);
        }
    }
    for (int off = 32; off > 0; off >>= 1) {
        for (int a = 0; a < 3; ++a) {
            mn[a] = fminf(mn[a], __shfl_xor(mn[a], off, 64));
            mx[a] = fmaxf(mx[a], __shfl_xor(mx[a], off, 64));
        }
    }
    const int wv = t >> 6, ln = t & 63;
    if (ln == 0) for (int a = 0; a < 3; ++a) { red[a][wv] = mn[a]; red[3+a][wv] = mx[a]; }
    __syncthreads();
    if (t == 0) {
        for (int a = 0; a < 3; ++a) {
            float lo = fminf(fminf(red[a][0], red[a][1]), fminf(red[a][2], red[a][3]));
            float hi = fmaxf(fmaxf(red[3+a][0], red[3+a][1]), fmaxf(red[3+a][2], red[3+a][3]));
            aabb[a*2] = lo; aabb[a*2+1] = hi;
        }
    }
}

// Per-atom top-24 + fused RBF. Matches jax.lax.top_k tie-break (key = (dist, flat f=s*NA+j)).
__global__ __launch_bounds__(256) void knn_kernel(const float* __restrict__ cart,
        const float* __restrict__ sv, const float* __restrict__ aabb,
        int* __restrict__ dstl, ushort* __restrict__ rbf16) {
    __shared__ float sx[NA], sy[NA], sz[NA];
    __shared__ float sd2[KCAP];
    __shared__ int   sf[KCAP];
    __shared__ float stx[27], sty[27], stz[27];
    __shared__ int   ssi[27];
    __shared__ float sde[KN];
    __shared__ int   nsh, scnt;
    const int t = threadIdx.x, i = blockIdx.x;
    for (int j = t; j < NA; j += 256) {
        sx[j] = cart[j*3]; sy[j] = cart[j*3+1]; sz[j] = cart[j*3+2];
    }
    __syncthreads();
    const float cx = sx[i], cy = sy[i], cz = sz[i];
    const float lox = aabb[0], hix = aabb[1], loy = aabb[2], hiy = aabb[3],
                loz = aabb[4], hiz = aabb[5];
    float R = 2.8f;
    int cnt = 0;
    for (int attempt = 0; attempt < 8; ++attempt) {
        const float R2 = R * R;
        if (t == 0) { nsh = 0; scnt = 0; }
        __syncthreads();
        if (t < 27) {   // per-shift prune: min dist from T=cart_i - sv_s to AABB(cart)
            float tx = cx - sv[t*3], ty = cy - sv[t*3+1], tz = cz - sv[t*3+2];
            float dx = fmaxf(fmaxf(lox-tx, tx-hix), 0.0f);
            float dy = fmaxf(fmaxf(loy-ty, ty-hiy), 0.0f);
            float dz = fmaxf(fmaxf(loz-tz, tz-hiz), 0.0f);
            if (dx*dx + dy*dy + dz*dz <= R2) {
                int s = atomicAdd(&nsh, 1);
                stx[s] = tx; sty[s] = ty; stz[s] = tz; ssi[s] = t;
            }
        }
        __syncthreads();
        const int ns = nsh;
        for (int q = 0; q < ns; ++q) {
            const float tx = stx[q], ty = sty[q], tz = stz[q];
            const int fb = ssi[q] << 11;     // s * NA
            for (int j = t; j < NA; j += 256) {
                float dx = sx[j]-tx, dy = sy[j]-ty, dz = sz[j]-tz;
                float d2 = fmaf(dx, dx, fmaf(dy, dy, dz*dz));
                if (d2 < R2 && d2 > 1e-4f) {
                    int slot = atomicAdd(&scnt, 1);
                    if (slot < KCAP) { sd2[slot] = d2; sf[slot] = fb + j; }
                }
            }
        }
        __syncthreads();
        cnt = min(scnt, KCAP);
        if (cnt >= KN) break;
        R = fminf(R * 1.6f, 8.0f);
        __syncthreads();
    }
    if (t < 64) {   // single-wave extraction: 24 rounds of shfl argmin, no barriers
        for (int k = 0; k < KN; ++k) {
            unsigned long long best = ~0ull;
            for (int q = t; q < cnt; q += 64) {
                unsigned long long key = ((unsigned long long)__float_as_uint(sd2[q]) << 26)
                                       | ((unsigned long long)(unsigned)sf[q] << 10) | (unsigned)q;
                best = best < key ? best : key;
            }
            for (int off = 32; off > 0; off >>= 1) {
                unsigned long long o = __shfl_xor(best, off, 64);
                best = best < o ? best : o;
            }
            if (t == 0) {
                int slot = (int)(best & 1023u);
                dstl[i*KN + k] = sf[slot] & (NA-1);
                sde[k]         = sqrtf(sd2[slot]);
                sd2[slot] = INFINITY;
            }
        }
    }
    __syncthreads();
    // fused RBF for this block's 24 edges
    for (int idx = t; idx < KN*EDIM; idx += 256) {
        const int k = idx >> 6, c = idx & 63;
        const float d = sde[k];
        const float center = (8.0f/63.0f) * (float)c;
        const float diff = d - center;
        const float g = expf(diff*diff * -32.0f);
        const float cv = 0.5f * (cosf(d * (float)(M_PI/8.0)) + 1.0f);
        rbf16[(size_t)(i*KN + k)*EDIM + c] = f2b(g * cv);
    }
}

// CSR build: atomic scatter (counts deterministic) then per-node ascending sort.
__global__ void scatter_kernel(const int* __restrict__ dstl, int* __restrict__ ccnt,
                               int* __restrict__ cedg) {
    int e = blockIdx.x*256 + threadIdx.x;
    if (e >= NE) return;
    int j = dstl[e];
    int slot = atomicAdd(&ccnt[j], 1);
    if (slot < MAXDEG) cedg[(size_t)j*MAXDEG + slot] = e;
}

// one wave per node: 64-lane bitonic sort (ascending), serial fallback for cnt>64
__global__ void csort_kernel(const int* __restrict__ ccnt, int* __restrict__ cedg) {
    const int j = blockIdx.x*4 + (threadIdx.x >> 6);
    const int lane = threadIdx.x & 63;
    const int cnt = min(ccnt[j], MAXDEG);
    if (cnt <= 64) {
        int v = (lane < cnt) ? cedg[(size_t)j*MAXDEG + lane] : 0x7FFFFFFF;
#pragma unroll
        for (int k = 2; k <= 64; k <<= 1) {
#pragma unroll
            for (int s = k >> 1; s > 0; s >>= 1) {
                int o = __shfl_xor(v, s, 64);
                const bool up = ((lane & k) == 0);
                const bool lowhalf = ((lane & s) == 0);
                v = ((lowhalf == up) ? min(v, o) : max(v, o));
            }
        }
        if (lane < cnt) cedg[(size_t)j*MAXDEG + lane] = v;
    } else if (lane == 0) {
        int* L = cedg + (size_t)j*MAXDEG;
        for (int a = 1; a < cnt; ++a) {
            int v = L[a]; int b = a - 1;
            while (b >= 0 && L[b] > v) { L[b+1] = L[b]; --b; }
            L[b+1] = v;
        }
    }
}

__global__ void nf_init_kernel(const int* __restrict__ atom_types, const float* __restrict__ ts,
                               const float* __restrict__ emb, const float* __restrict__ tW,
                               const float* __restrict__ tb, float* __restrict__ nf,
                               ushort* __restrict__ nf16) {
    int i = blockIdx.x, c = threadIdx.x;  // 128 threads
    float acc = emb[atom_types[i]*NDIM + c] + tb[c];
    for (int kk = 0; kk < 128; ++kk) acc += ts[i*128 + kk] * tW[kk*NDIM + c];
    nf[i*NDIM + c] = acc;
    nf16[i*NDIM + c] = f2b(acc);
}

// single kernel transposing+converting all 5 weight tensors (all layers): Wt[l][n][k]=bf16(W[l][k][n])
__global__ void wprep_all(const float* __restrict__ eW1, const float* __restrict__ eW2,
                          const float* __restrict__ cW1, const float* __restrict__ nW1,
                          const float* __restrict__ nW2,
                          ushort* __restrict__ eW1t, ushort* __restrict__ eW2t,
                          ushort* __restrict__ cW1t, ushort* __restrict__ nW1t,
                          ushort* __restrict__ nW2t) {
    int idx = blockIdx.x*256 + threadIdx.x;
    const float* W; ushort* Wt; int Kk, Nn, rel;
    if (idx < 327680)       { W=eW1; Wt=eW1t; Kk=320; Nn=256; rel=idx; }
    else if (idx < 589824)  { W=eW2; Wt=eW2t; Kk=256; Nn=256; rel=idx-327680; }
    else if (idx < 720896)  { W=cW1; Wt=cW1t; Kk=256; Nn=128; rel=idx-589824; }
    else if (idx < 1114112) { W=nW1; Wt=nW1t; Kk=384; Nn=256; rel=idx-720896; }
    else if (idx < 1245184) { W=nW2; Wt=nW2t; Kk=256; Nn=128; rel=idx-1114112; }
    else return;
    const int per = Kk*Nn;
    const int l = rel/per, r2 = rel - l*per;
    const int n = r2 / Kk, k = r2 - n*Kk;
    Wt[rel] = f2b(W[(size_t)l*per + (size_t)k*Nn + n]);
}

// bf16 MFMA GEMM, 128x128 tile, BK=32, 4 waves (64x64 each), double-buffered LDS.
// Staging: global_load_lds dwordx4, linear LDS [128][32], chunk-XOR g = c ^ ((r>>1)&3)
// pre-applied on the per-lane GLOBAL source; ds_read applies the same XOR (conflict-free).
// AMODE: 0 dense A | 1 ef-gather [nf16[src]|nf16[dst]|rbf16] | 2 ncat [nf16|aggr16]
// EPI:   0 bias+silu -> bf16 | 2 bias+res(fp32) -> fp32 Cf AND bf16 C16
//        3 fused wdot: wv[row] = sum_col silu(acc+bias)*cW2[col] + cb2 (no C write)
template<int AMODE, int EPI>
__global__ __launch_bounds__(256) void bgemm_kernel(
        const ushort* __restrict__ A, const ushort* __restrict__ nf16,
        const int* __restrict__ dstl, const ushort* __restrict__ rbf16,
        const ushort* __restrict__ aggr16, const ushort* __restrict__ Bt,
        const float* __restrict__ bias, const float* __restrict__ res,
        const float* __restrict__ cW2v, const float* __restrict__ cb2v,
        float* __restrict__ wvout,
        float* __restrict__ Cf, ushort* __restrict__ C16, int M, int Nn, int Kk) {
    __shared__ alignas(16) ushort As[2][128*32];
    __shared__ alignas(16) ushort Bs[2][128*32];
    __shared__ int sdst[128];
    const int t = threadIdx.x;
    const int wave = t >> 6, lane = t & 63;
    const int row0 = blockIdx.x*128, col0 = blockIdx.y*128;
    if (AMODE == 1) {
        if (t < 128) sdst[t] = dstl[row0 + t];
        __syncthreads();
    }
    const bool stA = wave < 2;
    const int wr = (wave >> 1)*64, wc = (wave & 1)*64;
    const int lr = lane & 15, g0 = lane >> 4;

    auto STAGE = [&](int buf, int k0) {
#pragma unroll
        for (int q = 0; q < 4; ++q) {
            const int r = (wave & 1)*64 + q*16 + (lane >> 2);   // tile row this lane loads
            const int g = (lane & 3) ^ ((r >> 1) & 3);          // source chunk (pre-swizzle)
            const int kg = k0 + g*8;
            const int ldsbase = ((wave & 1)*64 + q*16) * 32;
            if (stA) {
                const ushort* gp;
                if (AMODE == 0) {
                    gp = A + (size_t)(row0 + r)*Kk + kg;
                } else if (AMODE == 1) {
                    const int e = row0 + r;
                    if (kg < NDIM)        gp = nf16 + (size_t)(e/KN)*NDIM + kg;
                    else if (kg < 2*NDIM) gp = nf16 + (size_t)sdst[r]*NDIM + (kg - NDIM);
                    else                  gp = rbf16 + (size_t)e*EDIM + (kg - 2*NDIM);
                } else {
                    const int e = row0 + r;
                    if (kg < NDIM) gp = nf16 + (size_t)e*NDIM + kg;
                    else           gp = aggr16 + (size_t)e*HDIM + (kg - NDIM);
                }
                gl_lds(gp, &As[buf][ldsbase]);
            } else {
                gl_lds(Bt + (size_t)(col0 + r)*Kk + kg, &Bs[buf][ldsbase]);
            }
        }
    };

    f32x4 acc[4][4] = {};
    STAGE(0, 0);
    asm volatile("s_waitcnt vmcnt(0)" ::: "memory");
    __syncthreads();
    int cur = 0;
    for (int k0 = 0; k0 < Kk; k0 += 32) {
        if (k0 + 32 < Kk) STAGE(cur ^ 1, k0 + 32);
        bf16x8 af[4], bfr[4];
#pragma unroll
        for (int m = 0; m < 4; ++m) {
            const int rA = wr + m*16 + lr;
            af[m] = *reinterpret_cast<const bf16x8*>(&As[cur][rA*32 + (g0 ^ ((rA>>1)&3))*8]);
        }
#pragma unroll
        for (int n = 0; n < 4; ++n) {
            const int rB = wc + n*16 + lr;
            bfr[n] = *reinterpret_cast<const bf16x8*>(&Bs[cur][rB*32 + (g0 ^ ((rB>>1)&3))*8]);
        }
#pragma unroll
        for (int m = 0; m < 4; ++m)
#pragma unroll
            for (int n = 0; n < 4; ++n)
                acc[m][n] = __builtin_amdgcn_mfma_f32_16x16x32_bf16(af[m], bfr[n], acc[m][n], 0, 0, 0);
        asm volatile("s_waitcnt vmcnt(0)" ::: "memory");
        __syncthreads();
        cur ^= 1;
    }

    if constexpr (EPI == 3) {
        __shared__ float wred[2][128];
        float part[4][4];
#pragma unroll
        for (int m = 0; m < 4; ++m)
#pragma unroll
            for (int j = 0; j < 4; ++j) part[m][j] = 0.0f;
#pragma unroll
        for (int n = 0; n < 4; ++n) {
            const int cc = wc + n*16 + lr;       // col0 == 0 here (Nn=128)
            const float bb = bias[cc];
            const float cw = cW2v[cc];
#pragma unroll
            for (int m = 0; m < 4; ++m)
#pragma unroll
                for (int j = 0; j < 4; ++j)
                    part[m][j] += siluf(acc[m][n][j] + bb) * cw;
        }
#pragma unroll
        for (int off = 1; off < 16; off <<= 1)
#pragma unroll
            for (int m = 0; m < 4; ++m)
#pragma unroll
                for (int j = 0; j < 4; ++j)
                    part[m][j] += __shfl_xor(part[m][j], off, 64);
        if (lr == 0) {
#pragma unroll
            for (int m = 0; m < 4; ++m)
#pragma unroll
                for (int j = 0; j < 4; ++j)
                    wred[wave & 1][wr + m*16 + g0*4 + j] = part[m][j];
        }
        __syncthreads();
        if (t < 128) wvout[row0 + t] = wred[0][t] + wred[1][t] + cb2v[0];
        return;
    }

    // C/D layout: col = lane&15, row = (lane>>4)*4 + j
#pragma unroll
    for (int n = 0; n < 4; ++n) {
        const int cc = col0 + wc + n*16 + lr;
        const float bb = bias[cc];
#pragma unroll
        for (int m = 0; m < 4; ++m) {
#pragma unroll
            for (int j = 0; j < 4; ++j) {
                const int rr = row0 + wr + m*16 + (lane >> 4)*4 + j;
                float x = acc[m][n][j] + bb;
                if constexpr (EPI == 0) {
                    C16[(size_t)rr*Nn + cc] = f2b(siluf(x));
                } else {
                    x += res[(size_t)rr*Nn + cc];
                    Cf[(size_t)rr*Nn + cc] = x;
                    C16[(size_t)rr*Nn + cc] = f2b(x);
                }
            }
        }
    }
}

// aggr16[j,:] = bf16( sum over incoming edges of msg[e,:] ), one wave per node, 4 cols/lane
__global__ void aggr_kernel(const ushort* __restrict__ msg16, const int* __restrict__ ccnt,
                            const int* __restrict__ cedg, ushort* __restrict__ aggr16) {
    __shared__ int se[4][64];
    const int w = threadIdx.x >> 6, lane = threadIdx.x & 63;
    const int j = blockIdx.x*4 + w;
    const int cnt = min(ccnt[j], MAXDEG);
    se[w][lane] = (lane < cnt) ? cedg[(size_t)j*MAXDEG + lane] : 0;
    __syncthreads();
    const int c4 = lane*4;
    float s0 = 0, s1 = 0, s2 = 0, s3 = 0;
    const int lim = min(cnt, 64);
    for (int q = 0; q < lim; ++q) {
        const int e = se[w][q];
        ushort4 v = *reinterpret_cast<const ushort4*>(&msg16[(size_t)e*HDIM + c4]);
        s0 += b2f(v.x); s1 += b2f(v.y); s2 += b2f(v.z); s3 += b2f(v.w);
    }
    for (int q = 64; q < cnt; ++q) {
        const int e = cedg[(size_t)j*MAXDEG + q];
        ushort4 v = *reinterpret_cast<const ushort4*>(&msg16[(size_t)e*HDIM + c4]);
        s0 += b2f(v.x); s1 += b2f(v.y); s2 += b2f(v.z); s3 += b2f(v.w);
    }
    ushort4 o; o.x = f2b(s0); o.y = f2b(s1); o.z = f2b(s2); o.w = f2b(s3);
    *reinterpret_cast<ushort4*>(&aggr16[(size_t)j*HDIM + c4]) = o;
}

__global__ void coords_kernel(const float* __restrict__ cold, const float* __restrict__ wv,
                              const int* __restrict__ ccnt, const int* __restrict__ cedg,
                              float* __restrict__ cnew) {
    int j = blockIdx.x*256 + threadIdx.x;
    if (j >= NA) return;
    float jx = cold[j*3], jy = cold[j*3+1], jz = cold[j*3+2];
    float dx = 0, dy = 0, dz = 0;
    int cnt = min(ccnt[j], MAXDEG);
    for (int q = 0; q < cnt; ++q) {
        int e = cedg[(size_t)j*MAXDEG + q];
        int si = e / KN;
        float ax = cold[si*3]   - jx;
        float ay = cold[si*3+1] - jy;
        float az = cold[si*3+2] - jz;
        float inv = wv[e] / (sqrtf(ax*ax + ay*ay + az*az) + 1e-8f);
        dx += inv*ax; dy += inv*ay; dz += inv*az;
    }
    cnew[j*3]   = jx + dx;
    cnew[j*3+1] = jy + dy;
    cnew[j*3+2] = jz + dz;
}

__global__ void copyout_kernel(const float* __restrict__ nf, const float* __restrict__ coords,
                               float* __restrict__ out) {
    int idx = blockIdx.x*256 + threadIdx.x;
    if (idx < NA*NDIM) out[idx] = nf[idx];
    else if (idx < NA*NDIM + NA*3) out[idx] = coords[idx - NA*NDIM];
}

extern "C" void kernel_launch(void* const* d_in, const int* in_sizes, int n_in,
                              void* d_out, int out_size, void* d_ws, size_t ws_size,
                              hipStream_t stream) {
    const int*   atom_types = (const int*)  d_in[0];
    const float* frac       = (const float*)d_in[1];
    const float* lengths    = (const float*)d_in[2];
    const float* angles     = (const float*)d_in[3];
    const float* timesteps  = (const float*)d_in[4];
    const float* emb        = (const float*)d_in[5];
    const float* tW         = (const float*)d_in[6];
    const float* tb         = (const float*)d_in[7];
    const float* eW1        = (const float*)d_in[8];
    const float* eb1        = (const float*)d_in[9];
    const float* eW2        = (const float*)d_in[10];
    const float* eb2        = (const float*)d_in[11];
    const float* nW1        = (const float*)d_in[12];
    const float* nb1        = (const float*)d_in[13];
    const float* nW2        = (const float*)d_in[14];
    const float* nb2        = (const float*)d_in[15];
    const float* cW1        = (const float*)d_in[16];
    const float* cb1        = (const float*)d_in[17];
    const float* cW2        = (const float*)d_in[18];
    const float* cb2        = (const float*)d_in[19];

    char* p = (char*)d_ws;
    auto alloc = [&](size_t bytes) { char* q = p; p += (bytes + 255) & ~(size_t)255; return q; };
    float*  sv    = (float*) alloc(81*4);
    float*  aabb  = (float*) alloc(6*4);
    float*  c0    = (float*) alloc((size_t)NA*3*4);
    float*  c1    = (float*) alloc((size_t)NA*3*4);
    float*  nf    = (float*) alloc((size_t)NA*NDIM*4);
    int*    dstl  = (int*)   alloc((size_t)NE*4);
    ushort* rbf16 = (ushort*)alloc((size_t)NE*EDIM*2);
    int*    ccnt  = (int*)   alloc((size_t)NA*4);
    int*    cedg  = (int*)   alloc((size_t)NA*MAXDEG*4);
    ushort* aggr16= (ushort*)alloc((size_t)NA*HDIM*2);
    ushort* t116  = (ushort*)alloc((size_t)NA*HDIM*2);
    float*  wv    = (float*) alloc((size_t)NE*4);
    ushort* nf16  = (ushort*)alloc((size_t)NA*NDIM*2);
    ushort* h116  = (ushort*)alloc((size_t)NE*HDIM*2);
    ushort* msg16 = (ushort*)alloc((size_t)NE*HDIM*2);
    ushort* eW1t  = (ushort*)alloc((size_t)NLAYER*(2*NDIM+EDIM)*HDIM*2);
    ushort* eW2t  = (ushort*)alloc((size_t)NLAYER*HDIM*HDIM*2);
    ushort* cW1t  = (ushort*)alloc((size_t)NLAYER*(HDIM/2)*HDIM*2);
    ushort* nW1t  = (ushort*)alloc((size_t)NLAYER*(NDIM+HDIM)*HDIM*2);
    ushort* nW2t  = (ushort*)alloc((size_t)NLAYER*HDIM*NDIM*2);

    setup_kernel<<<8, 256, 0, stream>>>(frac, lengths, angles, c0, sv);
    aabb_kernel<<<1, 256, 0, stream>>>(c0, aabb);
    knn_kernel<<<NA, 256, 0, stream>>>(c0, sv, aabb, dstl, rbf16);
    hipMemsetAsync(ccnt, 0, (size_t)NA*4, stream);
    scatter_kernel<<<NE/256, 256, 0, stream>>>(dstl, ccnt, cedg);
    csort_kernel<<<NA/4, 256, 0, stream>>>(ccnt, cedg);
    nf_init_kernel<<<NA, 128, 0, stream>>>(atom_types, timesteps, emb, tW, tb, nf, nf16);
    wprep_all<<<4864, 256, 0, stream>>>(eW1, eW2, cW1, nW1, nW2, eW1t, eW2t, cW1t, nW1t, nW2t);

    float* cin = c0; float* cout = c1;
    for (int l = 0; l < NLAYER; ++l) {
        const float* eb1l = eb1 + (size_t)l*HDIM;
        const float* eb2l = eb2 + (size_t)l*HDIM;
        const float* nb1l = nb1 + (size_t)l*HDIM;
        const float* nb2l = nb2 + (size_t)l*NDIM;
        const float* cb1l = cb1 + (size_t)l*(HDIM/2);
        const float* cW2l = cW2 + (size_t)l*(HDIM/2);
        const float* cb2l = cb2 + (size_t)l;

        // h1 = silu(ef @ eW1 + eb1)  [gather A]
        bgemm_kernel<1,0><<<dim3(NE/128, HDIM/128), 256, 0, stream>>>(
            nullptr, nf16, dstl, rbf16, nullptr, eW1t + (size_t)l*(2*NDIM+EDIM)*HDIM, eb1l,
            nullptr, nullptr, nullptr, nullptr, nullptr, h116, NE, HDIM, 2*NDIM+EDIM);
        // msg = silu(h1 @ eW2 + eb2)
        bgemm_kernel<0,0><<<dim3(NE/128, HDIM/128), 256, 0, stream>>>(
            h116, nullptr, nullptr, nullptr, nullptr, eW2t + (size_t)l*HDIM*HDIM, eb2l,
            nullptr, nullptr, nullptr, nullptr, nullptr, msg16, NE, HDIM, HDIM);
        // aggr = segment_sum(msg, dst)
        aggr_kernel<<<NA/4, 256, 0, stream>>>(msg16, ccnt, cedg, aggr16);
        // t1 = silu([nf|aggr] @ nW1 + nb1)
        bgemm_kernel<2,0><<<dim3(NA/128, HDIM/128), 256, 0, stream>>>(
            nullptr, nf16, nullptr, nullptr, aggr16, nW1t + (size_t)l*(NDIM+HDIM)*HDIM, nb1l,
            nullptr, nullptr, nullptr, nullptr, nullptr, t116, NA, HDIM, NDIM+HDIM);
        // nf = nf + t1 @ nW2 + nb2   (writes fp32 nf AND bf16 nf16)
        bgemm_kernel<0,2><<<dim3(NA/128, NDIM/128), 256, 0, stream>>>(
            t116, nullptr, nullptr, nullptr, nullptr, nW2t + (size_t)l*HDIM*NDIM, nb2l,
            nf, nullptr, nullptr, nullptr, nf, nf16, NA, NDIM, HDIM);
        // wv = silu(msg @ cW1 + cb1) @ cW2 + cb2   [fused wdot epilogue]
        bgemm_kernel<0,3><<<dim3(NE/128, 1), 256, 0, stream>>>(
            msg16, nullptr, nullptr, nullptr, nullptr, cW1t + (size_t)l*(HDIM/2)*HDIM, cb1l,
            nullptr, cW2l, cb2l, wv, nullptr, nullptr, NE, HDIM/2, HDIM);
        // coords update
        coords_kernel<<<(NA+255)/256, 256, 0, stream>>>(cin, wv, ccnt, cedg, cout);
        float* tmp = cin; cin = cout; cout = tmp;
    }
    copyout_kernel<<<(NA*NDIM + NA*3)/256, 256, 0, stream>>>(nf, cin, (float*)d_out);
}

// Round 5
// 525.996 us; speedup vs baseline: 3.5089x; 1.0004x over previous
//
#include <hip/hip_runtime.h>
#include <math.h>

#define NA 2048          // atoms
#define KN 24            // neighbors per atom
#define NE (NA*KN)       // edges = 49152
#define NDIM 128         // node dim
#define EDIM 64          // rbf dim
#define HDIM 256         // hidden dim
#define NLAYER 4
#define MAXDEG 256       // cap on in-degree for CSR
#define WCAP 512         // per-wave candidate buffer (E[hits]=109, 5-sigma ~160)

typedef __attribute__((ext_vector_type(8))) short bf16x8;
typedef __attribute__((ext_vector_type(4))) float f32x4;

__device__ __forceinline__ float siluf(float x) { return x / (1.0f + expf(-x)); }
__device__ __forceinline__ ushort f2b(float x) {  // RNE float->bf16
    unsigned u = __float_as_uint(x);
    return (ushort)((u + 0x7fffu + ((u >> 16) & 1u)) >> 16);
}
__device__ __forceinline__ float b2f(ushort h) { return __uint_as_float(((unsigned)h) << 16); }

// async global->LDS, 16B per lane. LDS dest = uniform base + lane*16 (linear).
__device__ __forceinline__ void gl_lds(const void* g, void* lds) {
    __builtin_amdgcn_global_load_lds(
        (const __attribute__((address_space(1))) unsigned int*)g,
        (__attribute__((address_space(3))) unsigned int*)lds, 16, 0, 0);
}

struct Lat { float lx, xy, xz, ly, yz, lz; };

__device__ __forceinline__ Lat make_lattice(const float* lengths, const float* angles) {
    const float deg = 0.017453292519943295f;
    float a = lengths[0], b = lengths[1], c = lengths[2];
    float al = angles[0]*deg, be = angles[1]*deg, ga = angles[2]*deg;
    Lat L;
    L.lx = a;
    L.xy = b * cosf(ga);
    L.xz = c * cosf(be);
    L.ly = b * sinf(ga);
    L.yz = (b*c*cosf(al) - L.xy*L.xz) / L.ly;
    L.lz = sqrtf(c*c - L.xz*L.xz - L.yz*L.yz);
    return L;
}

// writes AoS cart (for aabb/coords) and SoA cx/cy/cz (for knn)
__global__ void setup_kernel(const float* __restrict__ frac, const float* __restrict__ lengths,
                             const float* __restrict__ angles, float* __restrict__ cart,
                             float* __restrict__ cxg, float* __restrict__ cyg,
                             float* __restrict__ czg, float* __restrict__ sv) {
    int i = blockIdx.x*blockDim.x + threadIdx.x;
    Lat L = make_lattice(lengths, angles);
    if (i < NA) {
        float f0 = frac[i*3], f1 = frac[i*3+1], f2 = frac[i*3+2];
        float x = f0*L.lx + f1*L.xy + f2*L.xz;
        float y = f1*L.ly + f2*L.yz;
        float z = f2*L.lz;
        cart[i*3+0] = x; cart[i*3+1] = y; cart[i*3+2] = z;
        cxg[i] = x; cyg[i] = y; czg[i] = z;
    }
    if (i < 27) {
        float s0 = (float)(i/9 - 1), s1 = (float)((i/3)%3 - 1), s2 = (float)(i%3 - 1);
        sv[i*3+0] = s0*L.lx + s1*L.xy + s2*L.xz;
        sv[i*3+1] = s1*L.ly + s2*L.yz;
        sv[i*3+2] = s2*L.lz;
    }
}

// AABB of cart points (single block)
__global__ void aabb_kernel(const float* __restrict__ cart, float* __restrict__ aabb) {
    __shared__ float red[6][4];
    const int t = threadIdx.x;  // 256
    float mn[3] = {1e30f,1e30f,1e30f}, mx[3] = {-1e30f,-1e30f,-1e30f};
    for (int j = t; j < NA; j += 256) {
        for (int a = 0; a < 3; ++a) {
            float v = cart[j*3+a];
            mn[a] = fminf(mn[a], v); mx[a] = fmaxf(mx[a], v);
        }
    }
    for (int off = 32; off > 0; off >>= 1) {
        for (int a = 0; a < 3; ++a) {
            mn[a] = fminf(mn[a], __shfl_xor(mn[a], off, 64));
            mx[a] = fmaxf(mx[a], __shfl_xor(mx[a], off, 64));
        }
    }
    const int wv = t >> 6, ln = t & 63;
    if (ln == 0) for (int a = 0; a < 3; ++a) { red[a][wv] = mn[a]; red[3+a][wv] = mx[a]; }
    __syncthreads();
    if (t == 0) {
        for (int a = 0; a < 3; ++a) {
            float lo = fminf(fminf(red[a][0], red[a][1]), fminf(red[a][2], red[a][3]));
            float hi = fmaxf(fmaxf(red[3+a][0], red[3+a][1]), fmaxf(red[3+a][2], red[3+a][3]));
            aabb[a*2] = lo; aabb[a*2+1] = hi;
        }
    }
}

// Per-atom top-24 + fused RBF. One wave per atom (4 atoms/block), wave-autonomous:
// ballot-ranked candidate placement (deterministic, ascending flat idx), per-wave extraction.
// Matches jax.lax.top_k tie-break (key = (dist, flat f = s*NA + j)).
__global__ __launch_bounds__(256) void knn_kernel(const float* __restrict__ cxg,
        const float* __restrict__ cyg, const float* __restrict__ czg,
        const float* __restrict__ sv, const float* __restrict__ aabb,
        int* __restrict__ dstl, ushort* __restrict__ rbf16) {
    __shared__ float sx[NA], sy[NA], sz[NA];
    __shared__ float sd2[4][WCAP];
    __shared__ int   sf[4][WCAP];
    const int t = threadIdx.x, w = t >> 6, lane = t & 63;
    const int i = blockIdx.x*4 + w;
    for (int j = t; j < NA; j += 256) { sx[j] = cxg[j]; sy[j] = cyg[j]; sz[j] = czg[j]; }
    __syncthreads();
    const float cx = sx[i], cy = sy[i], cz = sz[i];
    const float lox = aabb[0], hix = aabb[1], loy = aabb[2], hiy = aabb[3],
                loz = aabb[4], hiz = aabb[5];
    // shift-frame coords for this atom (lane < 27)
    float tx = 0, ty = 0, tz = 0;
    if (lane < 27) {
        tx = cx - sv[lane*3]; ty = cy - sv[lane*3+1]; tz = cz - sv[lane*3+2];
    }
    float R = 2.8f;
    int cnt = 0;
    for (int attempt = 0; attempt < 8; ++attempt) {
        const float R2 = R * R;
        bool ok = false;
        if (lane < 27) {
            float dx = fmaxf(fmaxf(lox-tx, tx-hix), 0.0f);
            float dy = fmaxf(fmaxf(loy-ty, ty-hiy), 0.0f);
            float dz = fmaxf(fmaxf(loz-tz, tz-hiz), 0.0f);
            ok = (dx*dx + dy*dy + dz*dz) <= R2;
        }
        unsigned long long smask = __ballot(ok);
        cnt = 0;
        while (smask) {
            const int s = __builtin_ctzll(smask); smask &= smask - 1;
            const float txs = __shfl(tx, s, 64), tys = __shfl(ty, s, 64), tzs = __shfl(tz, s, 64);
            const int fb = s << 11;   // s * NA
            for (int j0 = 0; j0 < NA; j0 += 64) {
                const int j = j0 + lane;
                const float dx = sx[j]-txs, dy = sy[j]-tys, dz = sz[j]-tzs;
                const float d2 = fmaf(dx, dx, fmaf(dy, dy, dz*dz));
                const bool hit = (d2 < R2) & (d2 > 1e-4f);
                const unsigned long long m = __ballot(hit);
                const int rank = __popcll(m & ((1ull << lane) - 1ull));
                const int slot = cnt + rank;
                if (hit && slot < WCAP) { sd2[w][slot] = d2; sf[w][slot] = fb + j; }
                cnt += __popcll(m);
            }
        }
        cnt = min(cnt, WCAP);
        if (cnt >= KN) break;
        R = fminf(R * 1.6f, 8.0f);
    }
    float der[KN];
    for (int k = 0; k < KN; ++k) {
        unsigned long long best = ~0ull;
        for (int q = lane; q < cnt; q += 64) {
            // key: d2 bits (32) | flat idx (16) | slot (9)
            unsigned long long key = ((unsigned long long)__float_as_uint(sd2[w][q]) << 25)
                                   | ((unsigned long long)(unsigned)sf[w][q] << 9) | (unsigned)q;
            best = best < key ? best : key;
        }
        for (int off = 32; off > 0; off >>= 1) {
            unsigned long long o = __shfl_xor(best, off, 64);
            best = best < o ? best : o;
        }
        const int slot = (int)(best & 511u);
        der[k] = sqrtf(sd2[w][slot]);          // broadcast LDS read, all lanes
        if (lane == 0) {
            dstl[i*KN + k] = sf[w][slot] & (NA-1);
            sd2[w][slot] = INFINITY;
        }
    }
    // fused RBF: lane = rbf channel (EDIM == 64)
    const float center = (8.0f/63.0f) * (float)lane;
    for (int k = 0; k < KN; ++k) {
        const float d = der[k];
        const float diff = d - center;
        const float g = expf(diff*diff * -32.0f);
        const float cv = 0.5f * (cosf(d * (float)(M_PI/8.0)) + 1.0f);
        rbf16[(size_t)(i*KN + k)*EDIM + lane] = f2b(g * cv);
    }
}

// CSR build: atomic scatter (counts deterministic) then per-node ascending sort.
__global__ void scatter_kernel(const int* __restrict__ dstl, int* __restrict__ ccnt,
                               int* __restrict__ cedg) {
    int e = blockIdx.x*256 + threadIdx.x;
    if (e >= NE) return;
    int j = dstl[e];
    int slot = atomicAdd(&ccnt[j], 1);
    if (slot < MAXDEG) cedg[(size_t)j*MAXDEG + slot] = e;
}

// one wave per node: 64-lane bitonic sort (ascending), serial fallback for cnt>64
__global__ void csort_kernel(const int* __restrict__ ccnt, int* __restrict__ cedg) {
    const int j = blockIdx.x*4 + (threadIdx.x >> 6);
    const int lane = threadIdx.x & 63;
    const int cnt = min(ccnt[j], MAXDEG);
    if (cnt <= 64) {
        int v = (lane < cnt) ? cedg[(size_t)j*MAXDEG + lane] : 0x7FFFFFFF;
#pragma unroll
        for (int k = 2; k <= 64; k <<= 1) {
#pragma unroll
            for (int s = k >> 1; s > 0; s >>= 1) {
                int o = __shfl_xor(v, s, 64);
                const bool up = ((lane & k) == 0);
                const bool lowhalf = ((lane & s) == 0);
                v = ((lowhalf == up) ? min(v, o) : max(v, o));
            }
        }
        if (lane < cnt) cedg[(size_t)j*MAXDEG + lane] = v;
    } else if (lane == 0) {
        int* L = cedg + (size_t)j*MAXDEG;
        for (int a = 1; a < cnt; ++a) {
            int v = L[a]; int b = a - 1;
            while (b >= 0 && L[b] > v) { L[b+1] = L[b]; --b; }
            L[b+1] = v;
        }
    }
}

__global__ void nf_init_kernel(const int* __restrict__ atom_types, const float* __restrict__ ts,
                               const float* __restrict__ emb, const float* __restrict__ tW,
                               const float* __restrict__ tb, float* __restrict__ nf,
                               ushort* __restrict__ nf16) {
    int i = blockIdx.x, c = threadIdx.x;  // 128 threads
    float acc = emb[atom_types[i]*NDIM + c] + tb[c];
    for (int kk = 0; kk < 128; ++kk) acc += ts[i*128 + kk] * tW[kk*NDIM + c];
    nf[i*NDIM + c] = acc;
    nf16[i*NDIM + c] = f2b(acc);
}

// LDS-tiled transpose+convert: Wt[l][n][k] = bf16(W[l][k][n]). 64x64 tiles.
// tiles: eW1 5x4x4=80 | eW2 4x4x4=64 | cW1 4x2x4=32 | nW1 6x4x4=96 | nW2 4x2x4=32 -> 304
__global__ void wprep_all(const float* __restrict__ eW1, const float* __restrict__ eW2,
                          const float* __restrict__ cW1, const float* __restrict__ nW1,
                          const float* __restrict__ nW2,
                          ushort* __restrict__ eW1t, ushort* __restrict__ eW2t,
                          ushort* __restrict__ cW1t, ushort* __restrict__ nW1t,
                          ushort* __restrict__ nW2t) {
    __shared__ float tile[64][65];
    const int b = blockIdx.x;
    const float* W; ushort* Wt; int Kk, Nn, rel;
    if (b < 80)       { W = eW1; Wt = eW1t; Kk = 320; Nn = 256; rel = b; }
    else if (b < 144) { W = eW2; Wt = eW2t; Kk = 256; Nn = 256; rel = b - 80; }
    else if (b < 176) { W = cW1; Wt = cW1t; Kk = 256; Nn = 128; rel = b - 144; }
    else if (b < 272) { W = nW1; Wt = nW1t; Kk = 384; Nn = 256; rel = b - 176; }
    else              { W = nW2; Wt = nW2t; Kk = 256; Nn = 128; rel = b - 272; }
    const int kt = Kk >> 6, nt = Nn >> 6, per = kt*nt;
    const int l = rel / per, r2 = rel - l*per;
    const int k0 = (r2 / nt) * 64, n0 = (r2 - (r2/nt)*nt) * 64;
    const float* Wl = W + (size_t)l*Kk*Nn;
    ushort* Wtl = Wt + (size_t)l*Kk*Nn;
    const int tr = threadIdx.x >> 6, tc = threadIdx.x & 63;
#pragma unroll
    for (int q = 0; q < 16; ++q) {
        const int k = q*4 + tr;
        tile[k][tc] = Wl[(size_t)(k0 + k)*Nn + n0 + tc];
    }
    __syncthreads();
#pragma unroll
    for (int q = 0; q < 16; ++q) {
        const int n = q*4 + tr;
        Wtl[(size_t)(n0 + n)*Kk + k0 + tc] = f2b(tile[tc][n]);
    }
}

// bf16 MFMA GEMM, 128x128 tile, BK=32, 4 waves (64x64 each), double-buffered LDS with
// COUNTED vmcnt pipeline: each wave stages a quarter of BOTH As and Bs so its own
// vmcnt(4) certifies its contribution; next-tile loads stay in flight across compute.
// Staging: global_load_lds dwordx4, linear LDS [128][32], chunk-XOR g = c ^ ((r>>1)&3)
// pre-applied on the per-lane GLOBAL source; ds_read applies the same XOR (conflict-free).
// AMODE: 0 dense A | 1 ef-gather [nf16[src]|nf16[dst]|rbf16] | 2 ncat [nf16|aggr16]
// EPI:   0 bias+silu -> bf16 | 2 bias+res(fp32) -> fp32 Cf AND bf16 C16
//        3 fused wdot: wv[row] = sum_col silu(acc+bias)*cW2[col] + cb2 (no C write)
template<int AMODE, int EPI>
__global__ __launch_bounds__(256) void bgemm_kernel(
        const ushort* __restrict__ A, const ushort* __restrict__ nf16,
        const int* __restrict__ dstl, const ushort* __restrict__ rbf16,
        const ushort* __restrict__ aggr16, const ushort* __restrict__ Bt,
        const float* __restrict__ bias, const float* __restrict__ res,
        const float* __restrict__ cW2v, const float* __restrict__ cb2v,
        float* __restrict__ wvout,
        float* __restrict__ Cf, ushort* __restrict__ C16, int M, int Nn, int Kk) {
    __shared__ alignas(16) ushort As[2][128*32];
    __shared__ alignas(16) ushort Bs[2][128*32];
    __shared__ int sdst[128];
    const int t = threadIdx.x;
    const int wave = t >> 6, lane = t & 63;
    const int row0 = blockIdx.x*128, col0 = blockIdx.y*128;
    if (AMODE == 1) {
        if (t < 128) sdst[t] = dstl[row0 + t];
        __syncthreads();
    }
    const int wr = (wave >> 1)*64, wc = (wave & 1)*64;
    const int lr = lane & 15, g0 = lane >> 4;

    // wave stages 2x16 rows of A (q=0,1) and 2x16 rows of B (q=2,3)
    auto STAGE = [&](int buf, int k0) {
#pragma unroll
        for (int q = 0; q < 4; ++q) {
            const int rbase = (q & 1)*64 + wave*16;
            const int r = rbase + (lane >> 2);
            const int g = (lane & 3) ^ ((r >> 1) & 3);   // source chunk (pre-swizzle)
            const int kg = k0 + g*8;
            const int ldsbase = rbase * 32;
            if (q < 2) {
                const ushort* gp;
                if (AMODE == 0) {
                    gp = A + (size_t)(row0 + r)*Kk + kg;
                } else if (AMODE == 1) {
                    const int e = row0 + r;
                    if (kg < NDIM)        gp = nf16 + (size_t)(e/KN)*NDIM + kg;
                    else if (kg < 2*NDIM) gp = nf16 + (size_t)sdst[r]*NDIM + (kg - NDIM);
                    else                  gp = rbf16 + (size_t)e*EDIM + (kg - 2*NDIM);
                } else {
                    const int e = row0 + r;
                    if (kg < NDIM) gp = nf16 + (size_t)e*NDIM + kg;
                    else           gp = aggr16 + (size_t)e*HDIM + (kg - NDIM);
                }
                gl_lds(gp, &As[buf][ldsbase]);
            } else {
                gl_lds(Bt + (size_t)(col0 + r)*Kk + kg, &Bs[buf][ldsbase]);
            }
        }
    };

    f32x4 acc[4][4] = {};
    const int nk = Kk >> 5;
    STAGE(0, 0);                                   // 4 outstanding
    int cur = 0;
    for (int it = 0; it < nk; ++it) {
        if (it + 1 < nk) {
            STAGE(cur ^ 1, (it + 1) << 5);         // 8 outstanding
            asm volatile("s_waitcnt vmcnt(4)" ::: "memory");   // cur complete (own quarter)
        } else {
            asm volatile("s_waitcnt vmcnt(0)" ::: "memory");
        }
        __builtin_amdgcn_sched_barrier(0);
        __builtin_amdgcn_s_barrier();              // everyone's cur complete
        __builtin_amdgcn_sched_barrier(0);
        bf16x8 af[4], bfr[4];
#pragma unroll
        for (int m = 0; m < 4; ++m) {
            const int rA = wr + m*16 + lr;
            af[m] = *reinterpret_cast<const bf16x8*>(&As[cur][rA*32 + (g0 ^ ((rA>>1)&3))*8]);
        }
#pragma unroll
        for (int n = 0; n < 4; ++n) {
            const int rB = wc + n*16 + lr;
            bfr[n] = *reinterpret_cast<const bf16x8*>(&Bs[cur][rB*32 + (g0 ^ ((rB>>1)&3))*8]);
        }
#pragma unroll
        for (int m = 0; m < 4; ++m)
#pragma unroll
            for (int n = 0; n < 4; ++n)
                acc[m][n] = __builtin_amdgcn_mfma_f32_16x16x32_bf16(af[m], bfr[n], acc[m][n], 0, 0, 0);
        asm volatile("s_waitcnt lgkmcnt(0)" ::: "memory");   // reads of cur drained
        __builtin_amdgcn_sched_barrier(0);
        __builtin_amdgcn_s_barrier();              // safe for next STAGE to overwrite cur
        __builtin_amdgcn_sched_barrier(0);
        cur ^= 1;
    }

    if constexpr (EPI == 3) {
        __shared__ float wred[2][128];
        float part[4][4];
#pragma unroll
        for (int m = 0; m < 4; ++m)
#pragma unroll
            for (int j = 0; j < 4; ++j) part[m][j] = 0.0f;
#pragma unroll
        for (int n = 0; n < 4; ++n) {
            const int cc = wc + n*16 + lr;       // col0 == 0 here (Nn=128)
            const float bb = bias[cc];
            const float cw = cW2v[cc];
#pragma unroll
            for (int m = 0; m < 4; ++m)
#pragma unroll
                for (int j = 0; j < 4; ++j)
                    part[m][j] += siluf(acc[m][n][j] + bb) * cw;
        }
#pragma unroll
        for (int off = 1; off < 16; off <<= 1)
#pragma unroll
            for (int m = 0; m < 4; ++m)
#pragma unroll
                for (int j = 0; j < 4; ++j)
                    part[m][j] += __shfl_xor(part[m][j], off, 64);
        if (lr == 0) {
#pragma unroll
            for (int m = 0; m < 4; ++m)
#pragma unroll
                for (int j = 0; j < 4; ++j)
                    wred[wave & 1][wr + m*16 + g0*4 + j] = part[m][j];
        }
        __syncthreads();
        if (t < 128) wvout[row0 + t] = wred[0][t] + wred[1][t] + cb2v[0];
        return;
    }

    // C/D layout: col = lane&15, row = (lane>>4)*4 + j
#pragma unroll
    for (int n = 0; n < 4; ++n) {
        const int cc = col0 + wc + n*16 + lr;
        const float bb = bias[cc];
#pragma unroll
        for (int m = 0; m < 4; ++m) {
#pragma unroll
            for (int j = 0; j < 4; ++j) {
                const int rr = row0 + wr + m*16 + (lane >> 4)*4 + j;
                float x = acc[m][n][j] + bb;
                if constexpr (EPI == 0) {
                    C16[(size_t)rr*Nn + cc] = f2b(siluf(x));
                } else {
                    x += res[(size_t)rr*Nn + cc];
                    Cf[(size_t)rr*Nn + cc] = x;
                    C16[(size_t)rr*Nn + cc] = f2b(x);
                }
            }
        }
    }
}

// aggr16[j,:] = bf16( sum over incoming edges of msg[e,:] ), one wave per node, 4 cols/lane
__global__ void aggr_kernel(const ushort* __restrict__ msg16, const int* __restrict__ ccnt,
                            const int* __restrict__ cedg, ushort* __restrict__ aggr16) {
    __shared__ int se[4][64];
    const int w = threadIdx.x >> 6, lane = threadIdx.x & 63;
    const int j = blockIdx.x*4 + w;
    const int cnt = min(ccnt[j], MAXDEG);
    se[w][lane] = (lane < cnt) ? cedg[(size_t)j*MAXDEG + lane] : 0;
    __syncthreads();
    const int c4 = lane*4;
    float s0 = 0, s1 = 0, s2 = 0, s3 = 0;
    const int lim = min(cnt, 64);
    for (int q = 0; q < lim; ++q) {
        const int e = se[w][q];
        ushort4 v = *reinterpret_cast<const ushort4*>(&msg16[(size_t)e*HDIM + c4]);
        s0 += b2f(v.x); s1 += b2f(v.y); s2 += b2f(v.z); s3 += b2f(v.w);
    }
    for (int q = 64; q < cnt; ++q) {
        const int e = cedg[(size_t)j*MAXDEG + q];
        ushort4 v = *reinterpret_cast<const ushort4*>(&msg16[(size_t)e*HDIM + c4]);
        s0 += b2f(v.x); s1 += b2f(v.y); s2 += b2f(v.z); s3 += b2f(v.w);
    }
    ushort4 o; o.x = f2b(s0); o.y = f2b(s1); o.z = f2b(s2); o.w = f2b(s3);
    *reinterpret_cast<ushort4*>(&aggr16[(size_t)j*HDIM + c4]) = o;
}

__global__ void coords_kernel(const float* __restrict__ cold, const float* __restrict__ wv,
                              const int* __restrict__ ccnt, const int* __restrict__ cedg,
                              float* __restrict__ cnew) {
    int j = blockIdx.x*256 + threadIdx.x;
    if (j >= NA) return;
    float jx = cold[j*3], jy = cold[j*3+1], jz = cold[j*3+2];
    float dx = 0, dy = 0, dz = 0;
    int cnt = min(ccnt[j], MAXDEG);
    for (int q = 0; q < cnt; ++q) {
        int e = cedg[(size_t)j*MAXDEG + q];
        int si = e / KN;
        float ax = cold[si*3]   - jx;
        float ay = cold[si*3+1] - jy;
        float az = cold[si*3+2] - jz;
        float inv = wv[e] / (sqrtf(ax*ax + ay*ay + az*az) + 1e-8f);
        dx += inv*ax; dy += inv*ay; dz += inv*az;
    }
    cnew[j*3]   = jx + dx;
    cnew[j*3+1] = jy + dy;
    cnew[j*3+2] = jz + dz;
}

__global__ void copyout_kernel(const float* __restrict__ nf, const float* __restrict__ coords,
                               float* __restrict__ out) {
    int idx = blockIdx.x*256 + threadIdx.x;
    if (idx < NA*NDIM) out[idx] = nf[idx];
    else if (idx < NA*NDIM + NA*3) out[idx] = coords[idx - NA*NDIM];
}

extern "C" void kernel_launch(void* const* d_in, const int* in_sizes, int n_in,
                              void* d_out, int out_size, void* d_ws, size_t ws_size,
                              hipStream_t stream) {
    const int*   atom_types = (const int*)  d_in[0];
    const float* frac       = (const float*)d_in[1];
    const float* lengths    = (const float*)d_in[2];
    const float* angles     = (const float*)d_in[3];
    const float* timesteps  = (const float*)d_in[4];
    const float* emb        = (const float*)d_in[5];
    const float* tW         = (const float*)d_in[6];
    const float* tb         = (const float*)d_in[7];
    const float* eW1        = (const float*)d_in[8];
    const float* eb1        = (const float*)d_in[9];
    const float* eW2        = (const float*)d_in[10];
    const float* eb2        = (const float*)d_in[11];
    const float* nW1        = (const float*)d_in[12];
    const float* nb1        = (const float*)d_in[13];
    const float* nW2        = (const float*)d_in[14];
    const float* nb2        = (const float*)d_in[15];
    const float* cW1        = (const float*)d_in[16];
    const float* cb1        = (const float*)d_in[17];
    const float* cW2        = (const float*)d_in[18];
    const float* cb2        = (const float*)d_in[19];

    char* p = (char*)d_ws;
    auto alloc = [&](size_t bytes) { char* q = p; p += (bytes + 255) & ~(size_t)255; return q; };
    float*  sv    = (float*) alloc(81*4);
    float*  aabb  = (float*) alloc(6*4);
    float*  c0    = (float*) alloc((size_t)NA*3*4);
    float*  c1    = (float*) alloc((size_t)NA*3*4);
    float*  cxg   = (float*) alloc((size_t)NA*4);
    float*  cyg   = (float*) alloc((size_t)NA*4);
    float*  czg   = (float*) alloc((size_t)NA*4);
    float*  nf    = (float*) alloc((size_t)NA*NDIM*4);
    int*    dstl  = (int*)   alloc((size_t)NE*4);
    ushort* rbf16 = (ushort*)alloc((size_t)NE*EDIM*2);
    int*    ccnt  = (int*)   alloc((size_t)NA*4);
    int*    cedg  = (int*)   alloc((size_t)NA*MAXDEG*4);
    ushort* aggr16= (ushort*)alloc((size_t)NA*HDIM*2);
    ushort* t116  = (ushort*)alloc((size_t)NA*HDIM*2);
    float*  wv    = (float*) alloc((size_t)NE*4);
    ushort* nf16  = (ushort*)alloc((size_t)NA*NDIM*2);
    ushort* h116  = (ushort*)alloc((size_t)NE*HDIM*2);
    ushort* msg16 = (ushort*)alloc((size_t)NE*HDIM*2);
    ushort* eW1t  = (ushort*)alloc((size_t)NLAYER*(2*NDIM+EDIM)*HDIM*2);
    ushort* eW2t  = (ushort*)alloc((size_t)NLAYER*HDIM*HDIM*2);
    ushort* cW1t  = (ushort*)alloc((size_t)NLAYER*(HDIM/2)*HDIM*2);
    ushort* nW1t  = (ushort*)alloc((size_t)NLAYER*(NDIM+HDIM)*HDIM*2);
    ushort* nW2t  = (ushort*)alloc((size_t)NLAYER*HDIM*NDIM*2);

    setup_kernel<<<8, 256, 0, stream>>>(frac, lengths, angles, c0, cxg, cyg, czg, sv);
    aabb_kernel<<<1, 256, 0, stream>>>(c0, aabb);
    knn_kernel<<<NA/4, 256, 0, stream>>>(cxg, cyg, czg, sv, aabb, dstl, rbf16);
    hipMemsetAsync(ccnt, 0, (size_t)NA*4, stream);
    scatter_kernel<<<NE/256, 256, 0, stream>>>(dstl, ccnt, cedg);
    csort_kernel<<<NA/4, 256, 0, stream>>>(ccnt, cedg);
    nf_init_kernel<<<NA, 128, 0, stream>>>(atom_types, timesteps, emb, tW, tb, nf, nf16);
    wprep_all<<<304, 256, 0, stream>>>(eW1, eW2, cW1, nW1, nW2, eW1t, eW2t, cW1t, nW1t, nW2t);

    float* cin = c0; float* cout = c1;
    for (int l = 0; l < NLAYER; ++l) {
        const float* eb1l = eb1 + (size_t)l*HDIM;
        const float* eb2l = eb2 + (size_t)l*HDIM;
        const float* nb1l = nb1 + (size_t)l*HDIM;
        const float* nb2l = nb2 + (size_t)l*NDIM;
        const float* cb1l = cb1 + (size_t)l*(HDIM/2);
        const float* cW2l = cW2 + (size_t)l*(HDIM/2);
        const float* cb2l = cb2 + (size_t)l;

        // h1 = silu(ef @ eW1 + eb1)  [gather A]
        bgemm_kernel<1,0><<<dim3(NE/128, HDIM/128), 256, 0, stream>>>(
            nullptr, nf16, dstl, rbf16, nullptr, eW1t + (size_t)l*(2*NDIM+EDIM)*HDIM, eb1l,
            nullptr, nullptr, nullptr, nullptr, nullptr, h116, NE, HDIM, 2*NDIM+EDIM);
        // msg = silu(h1 @ eW2 + eb2)
        bgemm_kernel<0,0><<<dim3(NE/128, HDIM/128), 256, 0, stream>>>(
            h116, nullptr, nullptr, nullptr, nullptr, eW2t + (size_t)l*HDIM*HDIM, eb2l,
            nullptr, nullptr, nullptr, nullptr, nullptr, msg16, NE, HDIM, HDIM);
        // aggr = segment_sum(msg, dst)
        aggr_kernel<<<NA/4, 256, 0, stream>>>(msg16, ccnt, cedg, aggr16);
        // t1 = silu([nf|aggr] @ nW1 + nb1)
        bgemm_kernel<2,0><<<dim3(NA/128, HDIM/128), 256, 0, stream>>>(
            nullptr, nf16, nullptr, nullptr, aggr16, nW1t + (size_t)l*(NDIM+HDIM)*HDIM, nb1l,
            nullptr, nullptr, nullptr, nullptr, nullptr, t116, NA, HDIM, NDIM+HDIM);
        // nf = nf + t1 @ nW2 + nb2   (writes fp32 nf AND bf16 nf16)
        bgemm_kernel<0,2><<<dim3(NA/128, NDIM/128), 256, 0, stream>>>(
            t116, nullptr, nullptr, nullptr, nullptr, nW2t + (size_t)l*HDIM*NDIM, nb2l,
            nf, nullptr, nullptr, nullptr, nf, nf16, NA, NDIM, HDIM);
        // wv = silu(msg @ cW1 + cb1) @ cW2 + cb2   [fused wdot epilogue]
        bgemm_kernel<0,3><<<dim3(NE/128, 1), 256, 0, stream>>>(
            msg16, nullptr, nullptr, nullptr, nullptr, cW1t + (size_t)l*(HDIM/2)*HDIM, cb1l,
            nullptr, cW2l, cb2l, wv, nullptr, nullptr, NE, HDIM/2, HDIM);
        // coords update
        coords_kernel<<<(NA+255)/256, 256, 0, stream>>>(cin, wv, ccnt, cedg, cout);
        float* tmp = cin; cin = cout; cout = tmp;
    }
    copyout_kernel<<<(NA*NDIM + NA*3)/256, 256, 0, stream>>>(nf, cin, (float*)d_out);
}

// Round 6
// 436.636 us; speedup vs baseline: 4.2270x; 1.2047x over previous
//
#include <hip/hip_runtime.h>
#include <math.h>

#define NA 2048          // atoms
#define KN 24            // neighbors per atom
#define NE (NA*KN)       // edges = 49152
#define NDIM 128         // node dim
#define EDIM 64          // rbf dim
#define HDIM 256         // hidden dim
#define NLAYER 4
#define MAXDEG 256       // cap on in-degree for CSR

typedef __attribute__((ext_vector_type(8))) short bf16x8;
typedef __attribute__((ext_vector_type(4))) float f32x4;

__device__ __forceinline__ float siluf(float x) { return x / (1.0f + expf(-x)); }
__device__ __forceinline__ ushort f2b(float x) {  // RNE float->bf16
    unsigned u = __float_as_uint(x);
    return (ushort)((u + 0x7fffu + ((u >> 16) & 1u)) >> 16);
}
__device__ __forceinline__ float b2f(ushort h) { return __uint_as_float(((unsigned)h) << 16); }

// async global->LDS, 16B per lane. LDS dest = uniform base + lane*16 (linear).
__device__ __forceinline__ void gl_lds(const void* g, void* lds) {
    __builtin_amdgcn_global_load_lds(
        (const __attribute__((address_space(1))) unsigned int*)g,
        (__attribute__((address_space(3))) unsigned int*)lds, 16, 0, 0);
}

struct Lat { float lx, xy, xz, ly, yz, lz; };

__device__ __forceinline__ Lat make_lattice(const float* lengths, const float* angles) {
    const float deg = 0.017453292519943295f;
    float a = lengths[0], b = lengths[1], c = lengths[2];
    float al = angles[0]*deg, be = angles[1]*deg, ga = angles[2]*deg;
    Lat L;
    L.lx = a;
    L.xy = b * cosf(ga);
    L.xz = c * cosf(be);
    L.ly = b * sinf(ga);
    L.yz = (b*c*cosf(al) - L.xy*L.xz) / L.ly;
    L.lz = sqrtf(c*c - L.xz*L.xz - L.yz*L.yz);
    return L;
}

// writes AoS cart (for coords) and SoA cx/cy/cz (for knn)
__global__ void setup_kernel(const float* __restrict__ frac, const float* __restrict__ lengths,
                             const float* __restrict__ angles, float* __restrict__ cart,
                             float* __restrict__ cxg, float* __restrict__ cyg,
                             float* __restrict__ czg, float* __restrict__ sv) {
    int i = blockIdx.x*blockDim.x + threadIdx.x;
    Lat L = make_lattice(lengths, angles);
    if (i < NA) {
        float f0 = frac[i*3], f1 = frac[i*3+1], f2 = frac[i*3+2];
        float x = f0*L.lx + f1*L.xy + f2*L.xz;
        float y = f1*L.ly + f2*L.yz;
        float z = f2*L.lz;
        cart[i*3+0] = x; cart[i*3+1] = y; cart[i*3+2] = z;
        cxg[i] = x; cyg[i] = y; czg[i] = z;
    }
    if (i < 27) {
        float s0 = (float)(i/9 - 1), s1 = (float)((i/3)%3 - 1), s2 = (float)(i%3 - 1);
        sv[i*3+0] = s0*L.lx + s1*L.xy + s2*L.xz;
        sv[i*3+1] = s1*L.ly + s2*L.yz;
        sv[i*3+2] = s2*L.lz;
    }
}

// Per-atom top-24 + fused RBF. One 64-lane wave per atom, no barriers.
// Orthogonal cell fast path: minimum-image (valid since R < L/2), per-lane-private
// candidate buffers (no cross-lane ops in collect), register-resident extraction.
// Fallback (non-ortho or per-lane overflow): brute 27-shift ballot-rank compaction.
// Tie-break matches jax.lax.top_k: key = (d2, flat f = s*NA + j).
__global__ __launch_bounds__(64) void knn_kernel(
        const float* __restrict__ cxg, const float* __restrict__ cyg,
        const float* __restrict__ czg, const float* __restrict__ lengths,
        const float* __restrict__ angles, const float* __restrict__ sv,
        int* __restrict__ dstl, ushort* __restrict__ rbf16) {
    __shared__ float sd2L[16][64];
    __shared__ int   sfL[16][64];
    const int lane = threadIdx.x;
    const int i = blockIdx.x;
    Lat L = make_lattice(lengths, angles);
    const float deg = 0.017453292519943295f;
    const bool ortho = fabsf(cosf(angles[0]*deg)) < 1e-6f &&
                       fabsf(cosf(angles[1]*deg)) < 1e-6f &&
                       fabsf(cosf(angles[2]*deg)) < 1e-6f;
    const float cx = cxg[i], cy = cyg[i], cz = czg[i];
    const float invlx = 1.0f/L.lx, invly = 1.0f/L.ly, invlz = 1.0f/L.lz;
    float R = 2.8f;
    int mycnt = 0, cnt = 0;
    bool flatm = false;
    for (int attempt = 0; attempt < 8; ++attempt) {
        const float R2 = R*R;
        mycnt = 0;
        flatm = !ortho || (attempt == 7);
        if (!flatm) {
            // minimum-image collect: 32 iterations, no cross-lane ops
#pragma unroll 2
            for (int j0 = 0; j0 < NA; j0 += 64) {
                const int j = j0 + lane;
                const float dx = cxg[j] - cx, dy = cyg[j] - cy, dz = czg[j] - cz;
                const float kx = rintf(dx*invlx), ky = rintf(dy*invly), kz = rintf(dz*invlz);
                const float ex = dx - (kx*L.lx + ky*L.xy + kz*L.xz);
                const float ey = dy - (ky*L.ly + kz*L.yz);
                const float ez = dz - kz*L.lz;
                const float d2 = fmaf(ex,ex,fmaf(ey,ey,ez*ez));
                if (d2 < R2 && d2 > 1e-4f) {
                    const int s = (1-(int)kx)*9 + (1-(int)ky)*3 + (1-(int)kz);
                    if (mycnt < 16) { sd2L[mycnt][lane] = d2; sfL[mycnt][lane] = (s<<11) + j; }
                    ++mycnt;
                }
            }
            if (__ballot(mycnt > 16)) {
                flatm = true;            // per-lane overflow: redo with shared compaction
            } else {
                int tot = mycnt;
                for (int off = 32; off > 0; off >>= 1) tot += __shfl_xor(tot, off, 64);
                cnt = tot;
            }
        }
        if (flatm) {
            cnt = 0;
            for (int s = 0; s < 27; ++s) {
                const float svx = sv[s*3], svy = sv[s*3+1], svz = sv[s*3+2];
                for (int j0 = 0; j0 < NA; j0 += 64) {
                    const int j = j0 + lane;
                    const float ex = cxg[j] + svx - cx;
                    const float ey = cyg[j] + svy - cy;
                    const float ez = czg[j] + svz - cz;
                    const float d2 = fmaf(ex,ex,fmaf(ey,ey,ez*ez));
                    const bool hit = (d2 < R2) && (d2 > 1e-4f);
                    const unsigned long long m = __ballot(hit);
                    const int rank = __popcll(m & ((1ull<<lane)-1ull));
                    const int slot = cnt + rank;
                    if (hit && slot < 1024) { sd2L[slot>>6][slot&63] = d2; sfL[slot>>6][slot&63] = (s<<11)+j; }
                    cnt += __popcll(m);
                }
            }
            cnt = min(cnt, 1024);
        }
        if (cnt >= KN) break;
        R = fminf(R*1.6f, flatm ? 8.0f : 5.9f);
    }
    // load candidates into register keys: (d2 bits)<<20 | flat<<4 | q
    int vq;
    if (flatm) vq = (lane < cnt) ? min(16, ((cnt - 1 - lane) >> 6) + 1) : 0;
    else       vq = mycnt;           // ≤ 16 in this branch
    unsigned long long key[16];
#pragma unroll
    for (int q = 0; q < 16; ++q) {
        const float d2v = sd2L[q][lane];
        const int fl = sfL[q][lane];
        const unsigned long long kk = ((unsigned long long)__float_as_uint(d2v) << 20)
                                    | ((unsigned long long)(unsigned)fl << 4) | (unsigned)q;
        key[q] = (q < vq) ? kk : ~0ull;
    }
    float der[KN];
    for (int k = 0; k < KN; ++k) {
        unsigned long long lm = key[0];
#pragma unroll
        for (int q = 1; q < 16; ++q) lm = key[q] < lm ? key[q] : lm;
        for (int off = 32; off > 0; off >>= 1) {
            unsigned long long o = __shfl_xor(lm, off, 64);
            lm = o < lm ? o : lm;
        }
        der[k] = sqrtf(__uint_as_float((unsigned)(lm >> 20)));
        if (lane == 0) dstl[i*KN + k] = (int)((lm >> 4) & 2047u);   // j = flat & (NA-1)
#pragma unroll
        for (int q = 0; q < 16; ++q) if (key[q] == lm) key[q] = ~0ull;
    }
    // fused RBF: lane = rbf channel (EDIM == 64)
    const float center = (8.0f/63.0f) * (float)lane;
    for (int k = 0; k < KN; ++k) {
        const float d = der[k];
        const float diff = d - center;
        const float g = expf(diff*diff * -32.0f);
        const float cv = 0.5f * (cosf(d * (float)(M_PI/8.0)) + 1.0f);
        rbf16[(size_t)(i*KN + k)*EDIM + lane] = f2b(g * cv);
    }
}

// CSR build: atomic scatter (counts deterministic) then per-node ascending sort.
__global__ void scatter_kernel(const int* __restrict__ dstl, int* __restrict__ ccnt,
                               int* __restrict__ cedg) {
    int e = blockIdx.x*256 + threadIdx.x;
    if (e >= NE) return;
    int j = dstl[e];
    int slot = atomicAdd(&ccnt[j], 1);
    if (slot < MAXDEG) cedg[(size_t)j*MAXDEG + slot] = e;
}

// one wave per node: 64-lane bitonic sort (ascending), serial fallback for cnt>64
__global__ void csort_kernel(const int* __restrict__ ccnt, int* __restrict__ cedg) {
    const int j = blockIdx.x*4 + (threadIdx.x >> 6);
    const int lane = threadIdx.x & 63;
    const int cnt = min(ccnt[j], MAXDEG);
    if (cnt <= 64) {
        int v = (lane < cnt) ? cedg[(size_t)j*MAXDEG + lane] : 0x7FFFFFFF;
#pragma unroll
        for (int k = 2; k <= 64; k <<= 1) {
#pragma unroll
            for (int s = k >> 1; s > 0; s >>= 1) {
                int o = __shfl_xor(v, s, 64);
                const bool up = ((lane & k) == 0);
                const bool lowhalf = ((lane & s) == 0);
                v = ((lowhalf == up) ? min(v, o) : max(v, o));
            }
        }
        if (lane < cnt) cedg[(size_t)j*MAXDEG + lane] = v;
    } else if (lane == 0) {
        int* L = cedg + (size_t)j*MAXDEG;
        for (int a = 1; a < cnt; ++a) {
            int v = L[a]; int b = a - 1;
            while (b >= 0 && L[b] > v) { L[b+1] = L[b]; --b; }
            L[b+1] = v;
        }
    }
}

__global__ void nf_init_kernel(const int* __restrict__ atom_types, const float* __restrict__ ts,
                               const float* __restrict__ emb, const float* __restrict__ tW,
                               const float* __restrict__ tb, float* __restrict__ nf,
                               ushort* __restrict__ nf16) {
    int i = blockIdx.x, c = threadIdx.x;  // 128 threads
    float acc = emb[atom_types[i]*NDIM + c] + tb[c];
    for (int kk = 0; kk < 128; ++kk) acc += ts[i*128 + kk] * tW[kk*NDIM + c];
    nf[i*NDIM + c] = acc;
    nf16[i*NDIM + c] = f2b(acc);
}

// LDS-tiled transpose+convert: Wt[l][n][k] = bf16(W[l][k][n]). 64x64 tiles.
// tiles: eW1 5x4x4=80 | eW2 4x4x4=64 | cW1 4x2x4=32 | nW1 6x4x4=96 | nW2 4x2x4=32 -> 304
__global__ void wprep_all(const float* __restrict__ eW1, const float* __restrict__ eW2,
                          const float* __restrict__ cW1, const float* __restrict__ nW1,
                          const float* __restrict__ nW2,
                          ushort* __restrict__ eW1t, ushort* __restrict__ eW2t,
                          ushort* __restrict__ cW1t, ushort* __restrict__ nW1t,
                          ushort* __restrict__ nW2t) {
    __shared__ float tile[64][65];
    const int b = blockIdx.x;
    const float* W; ushort* Wt; int Kk, Nn, rel;
    if (b < 80)       { W = eW1; Wt = eW1t; Kk = 320; Nn = 256; rel = b; }
    else if (b < 144) { W = eW2; Wt = eW2t; Kk = 256; Nn = 256; rel = b - 80; }
    else if (b < 176) { W = cW1; Wt = cW1t; Kk = 256; Nn = 128; rel = b - 144; }
    else if (b < 272) { W = nW1; Wt = nW1t; Kk = 384; Nn = 256; rel = b - 176; }
    else              { W = nW2; Wt = nW2t; Kk = 256; Nn = 128; rel = b - 272; }
    const int kt = Kk >> 6, nt = Nn >> 6, per = kt*nt;
    const int l = rel / per, r2 = rel - l*per;
    const int k0 = (r2 / nt) * 64, n0 = (r2 - (r2/nt)*nt) * 64;
    const float* Wl = W + (size_t)l*Kk*Nn;
    ushort* Wtl = Wt + (size_t)l*Kk*Nn;
    const int tr = threadIdx.x >> 6, tc = threadIdx.x & 63;
#pragma unroll
    for (int q = 0; q < 16; ++q) {
        const int k = q*4 + tr;
        tile[k][tc] = Wl[(size_t)(k0 + k)*Nn + n0 + tc];
    }
    __syncthreads();
#pragma unroll
    for (int q = 0; q < 16; ++q) {
        const int n = q*4 + tr;
        Wtl[(size_t)(n0 + n)*Kk + k0 + tc] = f2b(tile[tc][n]);
    }
}

// bf16 MFMA GEMM, 128x128 tile, BK=32, 4 waves (64x64 each), double-buffered LDS with
// counted-vmcnt pipeline (each wave stages a quarter of As and Bs; vmcnt(4) certifies cur).
// Staging: global_load_lds dwordx4, linear LDS [128][32], chunk-XOR g = c ^ ((r>>1)&3)
// pre-applied on the per-lane GLOBAL source; ds_read applies the same XOR (conflict-free).
// AMODE: 0 dense A | 1 ef-gather [nf16[src]|nf16[dst]|rbf16] | 2 ncat [nf16|aggr16]
// EPI:   0 bias+silu -> bf16 | 2 bias+res(fp32) -> fp32 Cf AND bf16 C16
//        3 fused wdot: wv[row] = sum_col silu(acc+bias)*cW2[col] + cb2 (no C write)
template<int AMODE, int EPI>
__global__ __launch_bounds__(256) void bgemm_kernel(
        const ushort* __restrict__ A, const ushort* __restrict__ nf16,
        const int* __restrict__ dstl, const ushort* __restrict__ rbf16,
        const ushort* __restrict__ aggr16, const ushort* __restrict__ Bt,
        const float* __restrict__ bias, const float* __restrict__ res,
        const float* __restrict__ cW2v, const float* __restrict__ cb2v,
        float* __restrict__ wvout,
        float* __restrict__ Cf, ushort* __restrict__ C16, int M, int Nn, int Kk) {
    __shared__ alignas(16) ushort As[2][128*32];
    __shared__ alignas(16) ushort Bs[2][128*32];
    __shared__ int sdst[128];
    const int t = threadIdx.x;
    const int wave = t >> 6, lane = t & 63;
    const int row0 = blockIdx.x*128, col0 = blockIdx.y*128;
    if (AMODE == 1) {
        if (t < 128) sdst[t] = dstl[row0 + t];
        __syncthreads();
    }
    const int wr = (wave >> 1)*64, wc = (wave & 1)*64;
    const int lr = lane & 15, g0 = lane >> 4;

    // wave stages 2x16 rows of A (q=0,1) and 2x16 rows of B (q=2,3)
    auto STAGE = [&](int buf, int k0) {
#pragma unroll
        for (int q = 0; q < 4; ++q) {
            const int rbase = (q & 1)*64 + wave*16;
            const int r = rbase + (lane >> 2);
            const int g = (lane & 3) ^ ((r >> 1) & 3);   // source chunk (pre-swizzle)
            const int kg = k0 + g*8;
            const int ldsbase = rbase * 32;
            if (q < 2) {
                const ushort* gp;
                if (AMODE == 0) {
                    gp = A + (size_t)(row0 + r)*Kk + kg;
                } else if (AMODE == 1) {
                    const int e = row0 + r;
                    if (kg < NDIM)        gp = nf16 + (size_t)(e/KN)*NDIM + kg;
                    else if (kg < 2*NDIM) gp = nf16 + (size_t)sdst[r]*NDIM + (kg - NDIM);
                    else                  gp = rbf16 + (size_t)e*EDIM + (kg - 2*NDIM);
                } else {
                    const int e = row0 + r;
                    if (kg < NDIM) gp = nf16 + (size_t)e*NDIM + kg;
                    else           gp = aggr16 + (size_t)e*HDIM + (kg - NDIM);
                }
                gl_lds(gp, &As[buf][ldsbase]);
            } else {
                gl_lds(Bt + (size_t)(col0 + r)*Kk + kg, &Bs[buf][ldsbase]);
            }
        }
    };

    f32x4 acc[4][4] = {};
    const int nk = Kk >> 5;
    STAGE(0, 0);                                   // 4 outstanding
    int cur = 0;
    for (int it = 0; it < nk; ++it) {
        if (it + 1 < nk) {
            STAGE(cur ^ 1, (it + 1) << 5);         // 8 outstanding
            asm volatile("s_waitcnt vmcnt(4)" ::: "memory");   // cur complete (own quarter)
        } else {
            asm volatile("s_waitcnt vmcnt(0)" ::: "memory");
        }
        __builtin_amdgcn_sched_barrier(0);
        __builtin_amdgcn_s_barrier();              // everyone's cur complete
        __builtin_amdgcn_sched_barrier(0);
        bf16x8 af[4], bfr[4];
#pragma unroll
        for (int m = 0; m < 4; ++m) {
            const int rA = wr + m*16 + lr;
            af[m] = *reinterpret_cast<const bf16x8*>(&As[cur][rA*32 + (g0 ^ ((rA>>1)&3))*8]);
        }
#pragma unroll
        for (int n = 0; n < 4; ++n) {
            const int rB = wc + n*16 + lr;
            bfr[n] = *reinterpret_cast<const bf16x8*>(&Bs[cur][rB*32 + (g0 ^ ((rB>>1)&3))*8]);
        }
#pragma unroll
        for (int m = 0; m < 4; ++m)
#pragma unroll
            for (int n = 0; n < 4; ++n)
                acc[m][n] = __builtin_amdgcn_mfma_f32_16x16x32_bf16(af[m], bfr[n], acc[m][n], 0, 0, 0);
        asm volatile("s_waitcnt lgkmcnt(0)" ::: "memory");   // reads of cur drained
        __builtin_amdgcn_sched_barrier(0);
        __builtin_amdgcn_s_barrier();              // safe for next STAGE to overwrite cur
        __builtin_amdgcn_sched_barrier(0);
        cur ^= 1;
    }

    if constexpr (EPI == 3) {
        __shared__ float wred[2][128];
        float part[4][4];
#pragma unroll
        for (int m = 0; m < 4; ++m)
#pragma unroll
            for (int j = 0; j < 4; ++j) part[m][j] = 0.0f;
#pragma unroll
        for (int n = 0; n < 4; ++n) {
            const int cc = wc + n*16 + lr;       // col0 == 0 here (Nn=128)
            const float bb = bias[cc];
            const float cw = cW2v[cc];
#pragma unroll
            for (int m = 0; m < 4; ++m)
#pragma unroll
                for (int j = 0; j < 4; ++j)
                    part[m][j] += siluf(acc[m][n][j] + bb) * cw;
        }
#pragma unroll
        for (int off = 1; off < 16; off <<= 1)
#pragma unroll
            for (int m = 0; m < 4; ++m)
#pragma unroll
                for (int j = 0; j < 4; ++j)
                    part[m][j] += __shfl_xor(part[m][j], off, 64);
        if (lr == 0) {
#pragma unroll
            for (int m = 0; m < 4; ++m)
#pragma unroll
                for (int j = 0; j < 4; ++j)
                    wred[wave & 1][wr + m*16 + g0*4 + j] = part[m][j];
        }
        __syncthreads();
        if (t < 128) wvout[row0 + t] = wred[0][t] + wred[1][t] + cb2v[0];
        return;
    }

    // C/D layout: col = lane&15, row = (lane>>4)*4 + j
#pragma unroll
    for (int n = 0; n < 4; ++n) {
        const int cc = col0 + wc + n*16 + lr;
        const float bb = bias[cc];
#pragma unroll
        for (int m = 0; m < 4; ++m) {
#pragma unroll
            for (int j = 0; j < 4; ++j) {
                const int rr = row0 + wr + m*16 + (lane >> 4)*4 + j;
                float x = acc[m][n][j] + bb;
                if constexpr (EPI == 0) {
                    C16[(size_t)rr*Nn + cc] = f2b(siluf(x));
                } else {
                    x += res[(size_t)rr*Nn + cc];
                    Cf[(size_t)rr*Nn + cc] = x;
                    C16[(size_t)rr*Nn + cc] = f2b(x);
                }
            }
        }
    }
}

// aggr16[j,:] = bf16( sum over incoming edges of msg[e,:] ), one wave per node, 4 cols/lane
__global__ void aggr_kernel(const ushort* __restrict__ msg16, const int* __restrict__ ccnt,
                            const int* __restrict__ cedg, ushort* __restrict__ aggr16) {
    __shared__ int se[4][64];
    const int w = threadIdx.x >> 6, lane = threadIdx.x & 63;
    const int j = blockIdx.x*4 + w;
    const int cnt = min(ccnt[j], MAXDEG);
    se[w][lane] = (lane < cnt) ? cedg[(size_t)j*MAXDEG + lane] : 0;
    __syncthreads();
    const int c4 = lane*4;
    float s0 = 0, s1 = 0, s2 = 0, s3 = 0;
    const int lim = min(cnt, 64);
    for (int q = 0; q < lim; ++q) {
        const int e = se[w][q];
        ushort4 v = *reinterpret_cast<const ushort4*>(&msg16[(size_t)e*HDIM + c4]);
        s0 += b2f(v.x); s1 += b2f(v.y); s2 += b2f(v.z); s3 += b2f(v.w);
    }
    for (int q = 64; q < cnt; ++q) {
        const int e = cedg[(size_t)j*MAXDEG + q];
        ushort4 v = *reinterpret_cast<const ushort4*>(&msg16[(size_t)e*HDIM + c4]);
        s0 += b2f(v.x); s1 += b2f(v.y); s2 += b2f(v.z); s3 += b2f(v.w);
    }
    ushort4 o; o.x = f2b(s0); o.y = f2b(s1); o.z = f2b(s2); o.w = f2b(s3);
    *reinterpret_cast<ushort4*>(&aggr16[(size_t)j*HDIM + c4]) = o;
}

// coords update: one wave per node, lanes parallel over edges, shfl-butterfly reduce
__global__ void coords_kernel(const float* __restrict__ cold, const float* __restrict__ wv,
                              const int* __restrict__ ccnt, const int* __restrict__ cedg,
                              float* __restrict__ cnew) {
    const int w = threadIdx.x >> 6, lane = threadIdx.x & 63;
    const int j = blockIdx.x*4 + w;
    const int cnt = min(ccnt[j], MAXDEG);
    const float jx = cold[j*3], jy = cold[j*3+1], jz = cold[j*3+2];
    float dx = 0, dy = 0, dz = 0;
    for (int q = lane; q < cnt; q += 64) {
        const int e = cedg[(size_t)j*MAXDEG + q];
        const int si = e / KN;
        const float ax = cold[si*3]   - jx;
        const float ay = cold[si*3+1] - jy;
        const float az = cold[si*3+2] - jz;
        const float inv = wv[e] / (sqrtf(ax*ax + ay*ay + az*az) + 1e-8f);
        dx += inv*ax; dy += inv*ay; dz += inv*az;
    }
    for (int off = 32; off > 0; off >>= 1) {
        dx += __shfl_xor(dx, off, 64);
        dy += __shfl_xor(dy, off, 64);
        dz += __shfl_xor(dz, off, 64);
    }
    if (lane == 0) {
        cnew[j*3]   = jx + dx;
        cnew[j*3+1] = jy + dy;
        cnew[j*3+2] = jz + dz;
    }
}

__global__ void copyout_kernel(const float* __restrict__ nf, const float* __restrict__ coords,
                               float* __restrict__ out) {
    int idx = blockIdx.x*256 + threadIdx.x;
    if (idx < NA*NDIM) out[idx] = nf[idx];
    else if (idx < NA*NDIM + NA*3) out[idx] = coords[idx - NA*NDIM];
}

extern "C" void kernel_launch(void* const* d_in, const int* in_sizes, int n_in,
                              void* d_out, int out_size, void* d_ws, size_t ws_size,
                              hipStream_t stream) {
    const int*   atom_types = (const int*)  d_in[0];
    const float* frac       = (const float*)d_in[1];
    const float* lengths    = (const float*)d_in[2];
    const float* angles     = (const float*)d_in[3];
    const float* timesteps  = (const float*)d_in[4];
    const float* emb        = (const float*)d_in[5];
    const float* tW         = (const float*)d_in[6];
    const float* tb         = (const float*)d_in[7];
    const float* eW1        = (const float*)d_in[8];
    const float* eb1        = (const float*)d_in[9];
    const float* eW2        = (const float*)d_in[10];
    const float* eb2        = (const float*)d_in[11];
    const float* nW1        = (const float*)d_in[12];
    const float* nb1        = (const float*)d_in[13];
    const float* nW2        = (const float*)d_in[14];
    const float* nb2        = (const float*)d_in[15];
    const float* cW1        = (const float*)d_in[16];
    const float* cb1        = (const float*)d_in[17];
    const float* cW2        = (const float*)d_in[18];
    const float* cb2        = (const float*)d_in[19];

    char* p = (char*)d_ws;
    auto alloc = [&](size_t bytes) { char* q = p; p += (bytes + 255) & ~(size_t)255; return q; };
    float*  sv    = (float*) alloc(81*4);
    float*  c0    = (float*) alloc((size_t)NA*3*4);
    float*  c1    = (float*) alloc((size_t)NA*3*4);
    float*  cxg   = (float*) alloc((size_t)NA*4);
    float*  cyg   = (float*) alloc((size_t)NA*4);
    float*  czg   = (float*) alloc((size_t)NA*4);
    float*  nf    = (float*) alloc((size_t)NA*NDIM*4);
    int*    dstl  = (int*)   alloc((size_t)NE*4);
    ushort* rbf16 = (ushort*)alloc((size_t)NE*EDIM*2);
    int*    ccnt  = (int*)   alloc((size_t)NA*4);
    int*    cedg  = (int*)   alloc((size_t)NA*MAXDEG*4);
    ushort* aggr16= (ushort*)alloc((size_t)NA*HDIM*2);
    ushort* t116  = (ushort*)alloc((size_t)NA*HDIM*2);
    float*  wv    = (float*) alloc((size_t)NE*4);
    ushort* nf16  = (ushort*)alloc((size_t)NA*NDIM*2);
    ushort* h116  = (ushort*)alloc((size_t)NE*HDIM*2);
    ushort* msg16 = (ushort*)alloc((size_t)NE*HDIM*2);
    ushort* eW1t  = (ushort*)alloc((size_t)NLAYER*(2*NDIM+EDIM)*HDIM*2);
    ushort* eW2t  = (ushort*)alloc((size_t)NLAYER*HDIM*HDIM*2);
    ushort* cW1t  = (ushort*)alloc((size_t)NLAYER*(HDIM/2)*HDIM*2);
    ushort* nW1t  = (ushort*)alloc((size_t)NLAYER*(NDIM+HDIM)*HDIM*2);
    ushort* nW2t  = (ushort*)alloc((size_t)NLAYER*HDIM*NDIM*2);

    setup_kernel<<<8, 256, 0, stream>>>(frac, lengths, angles, c0, cxg, cyg, czg, sv);
    knn_kernel<<<NA, 64, 0, stream>>>(cxg, cyg, czg, lengths, angles, sv, dstl, rbf16);
    hipMemsetAsync(ccnt, 0, (size_t)NA*4, stream);
    scatter_kernel<<<NE/256, 256, 0, stream>>>(dstl, ccnt, cedg);
    csort_kernel<<<NA/4, 256, 0, stream>>>(ccnt, cedg);
    nf_init_kernel<<<NA, 128, 0, stream>>>(atom_types, timesteps, emb, tW, tb, nf, nf16);
    wprep_all<<<304, 256, 0, stream>>>(eW1, eW2, cW1, nW1, nW2, eW1t, eW2t, cW1t, nW1t, nW2t);

    float* cin = c0; float* cout = c1;
    for (int l = 0; l < NLAYER; ++l) {
        const float* eb1l = eb1 + (size_t)l*HDIM;
        const float* eb2l = eb2 + (size_t)l*HDIM;
        const float* nb1l = nb1 + (size_t)l*HDIM;
        const float* nb2l = nb2 + (size_t)l*NDIM;
        const float* cb1l = cb1 + (size_t)l*(HDIM/2);
        const float* cW2l = cW2 + (size_t)l*(HDIM/2);
        const float* cb2l = cb2 + (size_t)l;

        // h1 = silu(ef @ eW1 + eb1)  [gather A]
        bgemm_kernel<1,0><<<dim3(NE/128, HDIM/128), 256, 0, stream>>>(
            nullptr, nf16, dstl, rbf16, nullptr, eW1t + (size_t)l*(2*NDIM+EDIM)*HDIM, eb1l,
            nullptr, nullptr, nullptr, nullptr, nullptr, h116, NE, HDIM, 2*NDIM+EDIM);
        // msg = silu(h1 @ eW2 + eb2)
        bgemm_kernel<0,0><<<dim3(NE/128, HDIM/128), 256, 0, stream>>>(
            h116, nullptr, nullptr, nullptr, nullptr, eW2t + (size_t)l*HDIM*HDIM, eb2l,
            nullptr, nullptr, nullptr, nullptr, nullptr, msg16, NE, HDIM, HDIM);
        // aggr = segment_sum(msg, dst)
        aggr_kernel<<<NA/4, 256, 0, stream>>>(msg16, ccnt, cedg, aggr16);
        // t1 = silu([nf|aggr] @ nW1 + nb1)
        bgemm_kernel<2,0><<<dim3(NA/128, HDIM/128), 256, 0, stream>>>(
            nullptr, nf16, nullptr, nullptr, aggr16, nW1t + (size_t)l*(NDIM+HDIM)*HDIM, nb1l,
            nullptr, nullptr, nullptr, nullptr, nullptr, t116, NA, HDIM, NDIM+HDIM);
        // nf = nf + t1 @ nW2 + nb2   (writes fp32 nf AND bf16 nf16)
        bgemm_kernel<0,2><<<dim3(NA/128, NDIM/128), 256, 0, stream>>>(
            t116, nullptr, nullptr, nullptr, nullptr, nW2t + (size_t)l*HDIM*NDIM, nb2l,
            nf, nullptr, nullptr, nullptr, nf, nf16, NA, NDIM, HDIM);
        // wv = silu(msg @ cW1 + cb1) @ cW2 + cb2   [fused wdot epilogue]
        bgemm_kernel<0,3><<<dim3(NE/128, 1), 256, 0, stream>>>(
            msg16, nullptr, nullptr, nullptr, nullptr, cW1t + (size_t)l*(HDIM/2)*HDIM, cb1l,
            nullptr, cW2l, cb2l, wv, nullptr, nullptr, NE, HDIM/2, HDIM);
        // coords update
        coords_kernel<<<NA/4, 256, 0, stream>>>(cin, wv, ccnt, cedg, cout);
        float* tmp = cin; cin = cout; cout = tmp;
    }
    copyout_kernel<<<(NA*NDIM + NA*3)/256, 256, 0, stream>>>(nf, cin, (float*)d_out);
}